// Round 1
// baseline (716.618 us; speedup 1.0000x reference)
//
#include <hip/hip_runtime.h>
#include <cstdint>
#include <cstddef>

// ---------------------------------------------------------------------------
// GCN 3-conv + MLP head, f32 baseline.
// out = log_softmax( relu(relu(relu(A@x W1+b1) -> A@· W2+b2) -> A@· W3+b3) fW1+fb1 ) fW2+fb2 )
// where A = D^-1/2 (Adj_w + I) D^-1/2 applied as aggregate-BEFORE-linear
// (associativity: A(xW) == (Ax)W), halving gather traffic since Fin<Fout.
// ---------------------------------------------------------------------------

__global__ __launch_bounds__(256) void k_init(float* deg, int* cnt, int* cursor, int n) {
    int i = blockIdx.x * blockDim.x + threadIdx.x;
    if (i < n) { deg[i] = 1.0f; cnt[i] = 0; cursor[i] = 0; }  // deg starts at 1 (self-loop w=1)
}

__global__ __launch_bounds__(256) void k_edge1(const int* __restrict__ src, const int* __restrict__ dst,
                                               const float* __restrict__ ew,
                                               float* deg, int* cnt, int E) {
    int e = blockIdx.x * blockDim.x + threadIdx.x;
    if (e < E) {
        int d = dst[e];
        atomicAdd(&deg[d], ew[e]);
        atomicAdd(&cnt[d], 1);
    }
}

__global__ __launch_bounds__(256) void k_dinv(const float* __restrict__ deg, float* __restrict__ dinv, int n) {
    int i = blockIdx.x * blockDim.x + threadIdx.x;
    if (i < n) { float d = deg[i]; dinv[i] = (d > 0.f) ? rsqrtf(d) : 0.f; }
}

// Exclusive prefix sum over cnt[0..n) -> rowptr[0..n], single workgroup.
__global__ __launch_bounds__(1024) void k_scan(const int* __restrict__ cnt, int* __restrict__ rowptr, int n) {
    __shared__ int s[1024];
    __shared__ int carry;
    int tid = threadIdx.x;
    if (tid == 0) carry = 0;
    __syncthreads();
    for (int base = 0; base < n; base += 1024) {
        int v = (base + tid < n) ? cnt[base + tid] : 0;
        s[tid] = v;
        __syncthreads();
        for (int off = 1; off < 1024; off <<= 1) {
            int t = (tid >= off) ? s[tid - off] : 0;
            __syncthreads();
            s[tid] += t;
            __syncthreads();
        }
        int incl = s[tid];
        int c = carry;
        if (base + tid < n) rowptr[base + tid] = c + incl - v;  // exclusive
        __syncthreads();
        if (tid == 0) carry = c + s[1023];
        __syncthreads();
    }
    if (tid == 0) rowptr[n] = carry;
}

__global__ __launch_bounds__(256) void k_fill(const int* __restrict__ src, const int* __restrict__ dst,
                                              const float* __restrict__ ew, const float* __restrict__ dinv,
                                              const int* __restrict__ rowptr, int* __restrict__ cursor,
                                              int* __restrict__ csr_src, float* __restrict__ csr_norm, int E) {
    int e = blockIdx.x * blockDim.x + threadIdx.x;
    if (e < E) {
        int d = dst[e], s = src[e];
        int p = atomicAdd(&cursor[d], 1);
        int idx = rowptr[d] + p;
        csr_src[idx] = s;
        csr_norm[idx] = dinv[s] * ew[e] * dinv[d];
    }
}

// out[i,:] = dinv[i]^2 * h[i,:] + sum_{j in in-edges(i)} norm_j * h[src_j,:]
// One wave (64 lanes) per node; V = F/64 floats per lane, vector loads.
template <int F>
__global__ __launch_bounds__(256) void k_agg(const float* __restrict__ h, const float* __restrict__ dinv,
                                             const int* __restrict__ rowptr, const int* __restrict__ csr_src,
                                             const float* __restrict__ csr_norm,
                                             float* __restrict__ out, int n) {
    constexpr int V = F / 64;
    int gw = (int)((blockIdx.x * blockDim.x + threadIdx.x) >> 6);
    int lane = threadIdx.x & 63;
    if (gw >= n) return;
    float di = dinv[gw];
    float w0 = di * di;
    float acc[V];
    const float* hp = h + (size_t)gw * F + lane * V;
    if constexpr (V == 4) {
        float4 x = *(const float4*)hp;
        acc[0] = w0 * x.x; acc[1] = w0 * x.y; acc[2] = w0 * x.z; acc[3] = w0 * x.w;
    } else if constexpr (V == 2) {
        float2 x = *(const float2*)hp;
        acc[0] = w0 * x.x; acc[1] = w0 * x.y;
    } else {
        acc[0] = w0 * hp[0];
    }
    int beg = rowptr[gw], end = rowptr[gw + 1];
    for (int j = beg; j < end; ++j) {
        int s = csr_src[j];
        float w = csr_norm[j];
        const float* q = h + (size_t)s * F + lane * V;
        if constexpr (V == 4) {
            float4 x = *(const float4*)q;
            acc[0] += w * x.x; acc[1] += w * x.y; acc[2] += w * x.z; acc[3] += w * x.w;
        } else if constexpr (V == 2) {
            float2 x = *(const float2*)q;
            acc[0] += w * x.x; acc[1] += w * x.y;
        } else {
            acc[0] += w * q[0];
        }
    }
    float* o = out + (size_t)gw * F + lane * V;
    if constexpr (V == 4)      *(float4*)o = make_float4(acc[0], acc[1], acc[2], acc[3]);
    else if constexpr (V == 2) *(float2*)o = make_float2(acc[0], acc[1]);
    else                       o[0] = acc[0];
}

// C[M,N] = act(A[M,K] @ B[K,N] + bias). 64x64 tile, 256 thr, 4x4 microtile.
template <bool RELU>
__global__ __launch_bounds__(256) void k_gemm(const float* __restrict__ A, const float* __restrict__ B,
                                              const float* __restrict__ bias, float* __restrict__ C,
                                              int M, int N, int K) {
    __shared__ __align__(16) float As[16][68];  // [k][m], padded stride 68 (16B-aligned rows)
    __shared__ __align__(16) float Bs[16][68];  // [k][n]
    int tid = threadIdx.x;
    int tx = tid & 15, ty = tid >> 4;
    int row0 = blockIdx.x * 64, col0 = blockIdx.y * 64;
    float acc[4][4] = {};
    int lar = tid >> 2;          // A tile row 0..63
    int lak = (tid & 3) << 2;    // A tile k   0,4,8,12
    int lbk = tid >> 4;          // B tile k   0..15
    int lbn = (tid & 15) << 2;   // B tile col 0..60
    for (int k0 = 0; k0 < K; k0 += 16) {
        float4 av = make_float4(0.f, 0.f, 0.f, 0.f);
        if (row0 + lar < M) av = *(const float4*)(A + (size_t)(row0 + lar) * K + (k0 + lak));
        float4 bv = make_float4(0.f, 0.f, 0.f, 0.f);
        if (col0 + lbn < N) bv = *(const float4*)(B + (size_t)(k0 + lbk) * N + (col0 + lbn));
        As[lak + 0][lar] = av.x;
        As[lak + 1][lar] = av.y;
        As[lak + 2][lar] = av.z;
        As[lak + 3][lar] = av.w;
        *(float4*)&Bs[lbk][lbn] = bv;
        __syncthreads();
#pragma unroll
        for (int k = 0; k < 16; ++k) {
            float4 a = *(const float4*)&As[k][ty << 2];
            float4 b = *(const float4*)&Bs[k][tx << 2];
            acc[0][0] += a.x * b.x; acc[0][1] += a.x * b.y; acc[0][2] += a.x * b.z; acc[0][3] += a.x * b.w;
            acc[1][0] += a.y * b.x; acc[1][1] += a.y * b.y; acc[1][2] += a.y * b.z; acc[1][3] += a.y * b.w;
            acc[2][0] += a.z * b.x; acc[2][1] += a.z * b.y; acc[2][2] += a.z * b.z; acc[2][3] += a.z * b.w;
            acc[3][0] += a.w * b.x; acc[3][1] += a.w * b.y; acc[3][2] += a.w * b.z; acc[3][3] += a.w * b.w;
        }
        __syncthreads();
    }
#pragma unroll
    for (int i = 0; i < 4; ++i) {
        int r = row0 + (ty << 2) + i;
        if (r >= M) continue;
#pragma unroll
        for (int j = 0; j < 4; ++j) {
            int c = col0 + (tx << 2) + j;
            if (c < N) {
                float v = acc[i][j] + bias[c];
                if (RELU) v = fmaxf(v, 0.f);
                C[(size_t)r * N + c] = v;
            }
        }
    }
}

__device__ inline float wred_max(float v) {
#pragma unroll
    for (int o = 32; o; o >>= 1) v = fmaxf(v, __shfl_xor(v, o));
    return v;
}
__device__ inline float wred_sum(float v) {
#pragma unroll
    for (int o = 32; o; o >>= 1) v += __shfl_xor(v, o);
    return v;
}

// log_softmax over 40 classes; one wave per row.
__global__ __launch_bounds__(256) void k_lsm(const float* __restrict__ in, float* __restrict__ out, int n) {
    int gw = (int)((blockIdx.x * blockDim.x + threadIdx.x) >> 6);
    int lane = threadIdx.x & 63;
    if (gw >= n) return;
    float v = (lane < 40) ? in[(size_t)gw * 40 + lane] : -INFINITY;
    float m = wred_max(v);
    float e = (lane < 40) ? __expf(v - m) : 0.f;
    float s = wred_sum(e);
    if (lane < 40) out[(size_t)gw * 40 + lane] = v - m - __logf(s);
}

extern "C" void kernel_launch(void* const* d_in, const int* in_sizes, int n_in,
                              void* d_out, int out_size, void* d_ws, size_t ws_size,
                              hipStream_t stream) {
    const float* x   = (const float*)d_in[0];
    const int*   ei  = (const int*)d_in[1];
    const float* ea  = (const float*)d_in[2];
    const float* W1  = (const float*)d_in[3];  const float* b1  = (const float*)d_in[4];
    const float* W2  = (const float*)d_in[5];  const float* b2  = (const float*)d_in[6];
    const float* W3  = (const float*)d_in[7];  const float* b3  = (const float*)d_in[8];
    const float* fW1 = (const float*)d_in[9];  const float* fb1 = (const float*)d_in[10];
    const float* fW2 = (const float*)d_in[11]; const float* fb2 = (const float*)d_in[12];

    int n = in_sizes[0] / 64;
    int E = in_sizes[1] / 2;
    const int* src = ei;
    const int* dst = ei + E;
    float* out = (float*)d_out;

    // workspace layout
    char* p = (char*)d_ws;
    auto alloc = [&](size_t bytes) -> char* {
        char* r = p;
        p += (bytes + 255) & ~(size_t)255;
        return r;
    };
    float* deg      = (float*)alloc((size_t)n * 4);
    float* dinv     = (float*)alloc((size_t)n * 4);
    int*   cnt      = (int*)alloc((size_t)n * 4);
    int*   cursor   = (int*)alloc((size_t)n * 4);
    int*   rowptr   = (int*)alloc((size_t)(n + 1) * 4);
    int*   csr_src  = (int*)alloc((size_t)E * 4);
    float* csr_norm = (float*)alloc((size_t)E * 4);
    float* AGG      = (float*)alloc((size_t)n * 256 * 4);  // also reused for logits [n,40]
    float* HA       = (float*)alloc((size_t)n * 512 * 4);
    float* HB       = (float*)alloc((size_t)n * 512 * 4);

    const int tb = 256;
    int nB = (n + tb - 1) / tb;
    int eB = (E + tb - 1) / tb;
    int waveB = ((size_t)n * 64 + tb - 1) / tb;

    // graph prep (per call; ~1% of total)
    k_init<<<nB, tb, 0, stream>>>(deg, cnt, cursor, n);
    k_edge1<<<eB, tb, 0, stream>>>(src, dst, ea, deg, cnt, E);
    k_dinv<<<nB, tb, 0, stream>>>(deg, dinv, n);
    k_scan<<<1, 1024, 0, stream>>>(cnt, rowptr, n);
    k_fill<<<eB, tb, 0, stream>>>(src, dst, ea, dinv, rowptr, cursor, csr_src, csr_norm, E);

    // conv1: agg(x)[n,64] -> @W1 relu -> HA[n,128]
    k_agg<64><<<waveB, tb, 0, stream>>>(x, dinv, rowptr, csr_src, csr_norm, AGG, n);
    {
        dim3 g((n + 63) / 64, 128 / 64);
        k_gemm<true><<<g, 256, 0, stream>>>(AGG, W1, b1, HA, n, 128, 64);
    }
    // conv2: agg(HA)[n,128] -> @W2 relu -> HB[n,256]
    k_agg<128><<<waveB, tb, 0, stream>>>(HA, dinv, rowptr, csr_src, csr_norm, AGG, n);
    {
        dim3 g((n + 63) / 64, 256 / 64);
        k_gemm<true><<<g, 256, 0, stream>>>(AGG, W2, b2, HB, n, 256, 128);
    }
    // conv3: agg(HB)[n,256] -> @W3 relu -> HA[n,512]
    k_agg<256><<<waveB, tb, 0, stream>>>(HB, dinv, rowptr, csr_src, csr_norm, AGG, n);
    {
        dim3 g((n + 63) / 64, 512 / 64);
        k_gemm<true><<<g, 256, 0, stream>>>(AGG, W3, b3, HA, n, 512, 256);
    }
    // fc1: HA @ fW1 relu -> HB[n,512]
    {
        dim3 g((n + 63) / 64, 512 / 64);
        k_gemm<true><<<g, 256, 0, stream>>>(HA, fW1, fb1, HB, n, 512, 512);
    }
    // fc2: HB @ fW2 -> logits in AGG[n,40]
    {
        dim3 g((n + 63) / 64, 1);
        k_gemm<false><<<g, 256, 0, stream>>>(HB, fW2, fb2, AGG, n, 40, 512);
    }
    // log_softmax -> out
    k_lsm<<<waveB, tb, 0, stream>>>(AGG, out, n);
}

// Round 2
// 590.443 us; speedup vs baseline: 1.2137x; 1.2137x over previous
//
#include <hip/hip_runtime.h>
#include <cstdint>
#include <cstddef>

// ---------------------------------------------------------------------------
// GCN 3-conv + MLP head. Split-bf16 MFMA GEMMs (A=Ah+Al, B=Bh+Bl, 3 products,
// f32 accumulate -> ~f32 accuracy at bf16 MFMA rate). Activations stored as
// hi/lo bf16 planes. Aggregate-before-linear (A(xW) == (Ax)W, Fin<Fout).
// ---------------------------------------------------------------------------

typedef short short8 __attribute__((ext_vector_type(8)));
typedef float v4f __attribute__((ext_vector_type(4)));
typedef unsigned short u16;

__device__ inline float bf2f(u16 h) {
    unsigned u = ((unsigned)h) << 16;
    return __builtin_bit_cast(float, u);
}
__device__ inline u16 f2bf(float v) {  // RTNE
    unsigned u = __builtin_bit_cast(unsigned, v);
    u += 0x7fffu + ((u >> 16) & 1u);
    return (u16)(u >> 16);
}
__device__ inline float lo16f(unsigned u) { return __builtin_bit_cast(float, u << 16); }
__device__ inline float hi16f(unsigned u) { return __builtin_bit_cast(float, u & 0xffff0000u); }

__device__ inline void gload_lds16(const void* g, void* l) {
    __builtin_amdgcn_global_load_lds(
        (const __attribute__((address_space(1))) unsigned int*)g,
        (__attribute__((address_space(3))) unsigned int*)l, 16, 0, 0);
}

// ------------------------------ graph prep --------------------------------

__global__ __launch_bounds__(256) void k_init(float* deg, int* cnt, int* cursor, int n) {
    int i = blockIdx.x * blockDim.x + threadIdx.x;
    if (i < n) { deg[i] = 1.0f; cnt[i] = 0; cursor[i] = 0; }
}

__global__ __launch_bounds__(256) void k_edge1(const int* __restrict__ src, const int* __restrict__ dst,
                                               const float* __restrict__ ew,
                                               float* deg, int* cnt, int E) {
    int e = blockIdx.x * blockDim.x + threadIdx.x;
    if (e < E) {
        int d = dst[e];
        atomicAdd(&deg[d], ew[e]);
        atomicAdd(&cnt[d], 1);
    }
}

__global__ __launch_bounds__(256) void k_dinv(const float* __restrict__ deg, float* __restrict__ dinv, int n) {
    int i = blockIdx.x * blockDim.x + threadIdx.x;
    if (i < n) {
        float d = deg[i];
        float r = (d > 0.f) ? rsqrtf(d) : 0.f;
        r = r * (1.5f - 0.5f * d * r * r);  // Newton: ~2^-24 rel err
        dinv[i] = r;
    }
}

__global__ __launch_bounds__(1024) void k_scan(const int* __restrict__ cnt, int* __restrict__ rowptr, int n) {
    __shared__ int s[1024];
    __shared__ int carry;
    int tid = threadIdx.x;
    if (tid == 0) carry = 0;
    __syncthreads();
    for (int base = 0; base < n; base += 1024) {
        int v = (base + tid < n) ? cnt[base + tid] : 0;
        s[tid] = v;
        __syncthreads();
        for (int off = 1; off < 1024; off <<= 1) {
            int t = (tid >= off) ? s[tid - off] : 0;
            __syncthreads();
            s[tid] += t;
            __syncthreads();
        }
        int incl = s[tid];
        int c = carry;
        if (base + tid < n) rowptr[base + tid] = c + incl - v;
        __syncthreads();
        if (tid == 0) carry = c + s[1023];
        __syncthreads();
    }
    if (tid == 0) rowptr[n] = carry;
}

__global__ __launch_bounds__(256) void k_fill(const int* __restrict__ src, const int* __restrict__ dst,
                                              const float* __restrict__ ew, const float* __restrict__ dinv,
                                              const int* __restrict__ rowptr, int* __restrict__ cursor,
                                              int* __restrict__ csr_src, float* __restrict__ csr_norm, int E) {
    int e = blockIdx.x * blockDim.x + threadIdx.x;
    if (e < E) {
        int d = dst[e], s = src[e];
        int p = atomicAdd(&cursor[d], 1);
        int idx = rowptr[d] + p;
        csr_src[idx] = s;
        csr_norm[idx] = dinv[s] * ew[e] * dinv[d];
    }
}

// Weight split+transpose: W[K,N] f32 -> Th,Tl[Np,K] bf16 (rows >= N zeroed).
__global__ __launch_bounds__(256) void k_wprep(const float* __restrict__ W, u16* __restrict__ Th,
                                               u16* __restrict__ Tl, int K, int N, int Np) {
    int i = blockIdx.x * blockDim.x + threadIdx.x;
    if (i >= Np * K) return;
    int nr = i / K, k = i % K;
    float v = (nr < N) ? W[(size_t)k * N + nr] : 0.f;
    u16 h = f2bf(v);
    Th[i] = h;
    Tl[i] = f2bf(v - bf2f(h));
}

// ------------------------------ aggregation -------------------------------

template <int F>
__device__ inline void gather_add(const u16* __restrict__ hh, const u16* __restrict__ hl,
                                  size_t base, float w, float* acc) {
    constexpr int W = F / 128;  // uint words per lane
    if constexpr (W == 1) {
        unsigned a = *(const unsigned*)(hh + base);
        unsigned b = *(const unsigned*)(hl + base);
        acc[0] += w * (lo16f(a) + lo16f(b));
        acc[1] += w * (hi16f(a) + hi16f(b));
    } else if constexpr (W == 2) {
        uint2 a = *(const uint2*)(hh + base);
        uint2 b = *(const uint2*)(hl + base);
        acc[0] += w * (lo16f(a.x) + lo16f(b.x));
        acc[1] += w * (hi16f(a.x) + hi16f(b.x));
        acc[2] += w * (lo16f(a.y) + lo16f(b.y));
        acc[3] += w * (hi16f(a.y) + hi16f(b.y));
    } else {
        uint4 a = *(const uint4*)(hh + base);
        uint4 b = *(const uint4*)(hl + base);
        acc[0] += w * (lo16f(a.x) + lo16f(b.x));
        acc[1] += w * (hi16f(a.x) + hi16f(b.x));
        acc[2] += w * (lo16f(a.y) + lo16f(b.y));
        acc[3] += w * (hi16f(a.y) + hi16f(b.y));
        acc[4] += w * (lo16f(a.z) + lo16f(b.z));
        acc[5] += w * (hi16f(a.z) + hi16f(b.z));
        acc[6] += w * (lo16f(a.w) + lo16f(b.w));
        acc[7] += w * (hi16f(a.w) + hi16f(b.w));
    }
}

template <int F>
__device__ inline void store_split(u16* __restrict__ oh, u16* __restrict__ ol,
                                   size_t base, const float* acc) {
    constexpr int V = F / 64;
    if constexpr (V == 1) {
        u16 h = f2bf(acc[0]);
        oh[base] = h;
        ol[base] = f2bf(acc[0] - bf2f(h));
    } else {
        unsigned wh[V / 2], wl[V / 2];
#pragma unroll
        for (int i = 0; i < V / 2; ++i) {
            u16 h0 = f2bf(acc[2 * i]), h1 = f2bf(acc[2 * i + 1]);
            u16 l0 = f2bf(acc[2 * i] - bf2f(h0)), l1 = f2bf(acc[2 * i + 1] - bf2f(h1));
            wh[i] = (unsigned)h0 | ((unsigned)h1 << 16);
            wl[i] = (unsigned)l0 | ((unsigned)l1 << 16);
        }
        if constexpr (V == 2) {
            *(unsigned*)(oh + base) = wh[0];
            *(unsigned*)(ol + base) = wl[0];
        } else if constexpr (V == 4) {
            *(uint2*)(oh + base) = make_uint2(wh[0], wh[1]);
            *(uint2*)(ol + base) = make_uint2(wl[0], wl[1]);
        } else {
            *(uint4*)(oh + base) = make_uint4(wh[0], wh[1], wh[2], wh[3]);
            *(uint4*)(ol + base) = make_uint4(wl[0], wl[1], wl[2], wl[3]);
        }
    }
}

// out[i,:] = dinv[i]^2*h[i,:] + sum_j norm_j*h[src_j,:]; split-bf16 in/out.
template <int F, bool IN_F32>
__global__ __launch_bounds__(256) void k_agg(const float* __restrict__ hf,
                                             const u16* __restrict__ hh, const u16* __restrict__ hl,
                                             const float* __restrict__ dinv, const int* __restrict__ rowptr,
                                             const int* __restrict__ csr_src, const float* __restrict__ csr_norm,
                                             u16* __restrict__ oh, u16* __restrict__ ol, int n) {
    constexpr int V = F / 64;
    int gw = (int)((blockIdx.x * blockDim.x + threadIdx.x) >> 6);
    int lane = threadIdx.x & 63;
    if (gw >= n) return;
    float di = dinv[gw], w0 = di * di;
    float acc[V];
#pragma unroll
    for (int v = 0; v < V; ++v) acc[v] = 0.f;
    if constexpr (IN_F32) {
        acc[0] = w0 * hf[(size_t)gw * F + lane];
    } else {
        gather_add<F>(hh, hl, (size_t)gw * F + lane * V, w0, acc);
    }
    int beg = rowptr[gw], end = rowptr[gw + 1];
    for (int j = beg; j < end; ++j) {
        int s = csr_src[j];
        float w = csr_norm[j];
        if constexpr (IN_F32)
            acc[0] += w * hf[(size_t)s * F + lane];
        else
            gather_add<F>(hh, hl, (size_t)s * F + lane * V, w, acc);
    }
    store_split<F>(oh, ol, (size_t)gw * F + lane * V, acc);
}

// ------------------------------ MFMA GEMM ---------------------------------
// C[M,N] = act(A @ B + bias), A as split planes [Mp,K], B as split transposed
// planes BT[Np,K]. 128x128 tile, BK=64, 4 waves (2x2), 16x16x32 bf16 MFMA,
// 3 products per frag pair. A staged via global_load_lds with XOR swizzle
// (linear LDS dest + inverse-swizzled global src); B frags straight from L2.
template <bool RELU, bool SPLIT_OUT>
__global__ __launch_bounds__(256) void k_mm(const u16* __restrict__ Ah, const u16* __restrict__ Al,
                                            const u16* __restrict__ BTh, const u16* __restrict__ BTl,
                                            const float* __restrict__ bias,
                                            u16* __restrict__ Ch, u16* __restrict__ Cl,
                                            float* __restrict__ Cf,
                                            int M, int N, int K, int nB, int nwg) {
    __shared__ u16 lsA[2][128 * 64];  // [plane][row*64 + k], XOR-swizzled slots

    // bijective XCD-aware block swizzle (m204)
    int wg = blockIdx.x;
    int q = nwg >> 3, r = nwg & 7;
    int xcd = wg & 7, lin = wg >> 3;
    int wgs = (xcd < r) ? (xcd * (q + 1) + lin) : (r * (q + 1) + (xcd - r) * q + lin);
    int bm = wgs / nB, bn = wgs % nB;

    int tid = threadIdx.x;
    int lane = tid & 63, wid = tid >> 6;
    int l16 = lane & 15, lhi = lane >> 4;
    int wm = (wid >> 1) * 64, wn = (wid & 1) * 64;
    int brow = bm * 128, bcol = bn * 128;

    v4f acc[4][4] = {};

    for (int k0 = 0; k0 < K; k0 += 64) {
        __syncthreads();  // previous iteration's LDS reads done
        // stage A hi/lo planes: 8 x global_load_lds(16B), swizzled source
#pragma unroll
        for (int p = 0; p < 2; ++p) {
            const u16* srcp = p ? Al : Ah;
#pragma unroll
            for (int i = 0; i < 4; ++i) {
                int b = i * 4096 + tid * 16;  // byte offset in 16KB plane tile
                int row = b >> 7;
                int s = ((b >> 4) & 7) ^ (row & 7);
                const u16* g = srcp + (size_t)(brow + row) * K + k0 + s * 8;
                gload_lds16(g, ((char*)&lsA[p][0]) + b);
            }
        }
        // B fragments from global (weights are L2-resident)
        short8 bh[2][4], bl[2][4];
#pragma unroll
        for (int ks = 0; ks < 2; ++ks)
#pragma unroll
            for (int f = 0; f < 4; ++f) {
                size_t off = (size_t)(bcol + wn + f * 16 + l16) * K + k0 + ks * 32 + lhi * 8;
                bh[ks][f] = *(const short8*)(BTh + off);
                bl[ks][f] = *(const short8*)(BTl + off);
            }
        __syncthreads();  // staging complete
#pragma unroll
        for (int ks = 0; ks < 2; ++ks) {
#pragma unroll
            for (int fm = 0; fm < 4; ++fm) {
                int row = wm + fm * 16 + l16;
                int sidx = (ks * 4 + lhi) ^ (row & 7);
                const u16* pa = &lsA[0][0] + row * 64 + sidx * 8;
                short8 ah = *(const short8*)pa;
                short8 al = *(const short8*)(pa + 128 * 64);
#pragma unroll
                for (int fn = 0; fn < 4; ++fn) {
                    acc[fm][fn] = __builtin_amdgcn_mfma_f32_16x16x32_bf16(ah, bh[ks][fn], acc[fm][fn], 0, 0, 0);
                    acc[fm][fn] = __builtin_amdgcn_mfma_f32_16x16x32_bf16(al, bh[ks][fn], acc[fm][fn], 0, 0, 0);
                    acc[fm][fn] = __builtin_amdgcn_mfma_f32_16x16x32_bf16(ah, bl[ks][fn], acc[fm][fn], 0, 0, 0);
                }
            }
        }
    }

    // epilogue: D[row][col], row=(lane>>4)*4+r, col=lane&15 per 16x16 frag
#pragma unroll
    for (int fn = 0; fn < 4; ++fn) {
        int col = bcol + wn + fn * 16 + l16;
        if (col >= N) continue;
        float bv = bias[col];
#pragma unroll
        for (int fm = 0; fm < 4; ++fm) {
#pragma unroll
            for (int rr = 0; rr < 4; ++rr) {
                int row = brow + wm + fm * 16 + lhi * 4 + rr;
                if (row >= M) continue;
                float v = acc[fm][fn][rr] + bv;
                if (RELU) v = fmaxf(v, 0.f);
                if (SPLIT_OUT) {
                    u16 h = f2bf(v);
                    Ch[(size_t)row * N + col] = h;
                    Cl[(size_t)row * N + col] = f2bf(v - bf2f(h));
                } else {
                    Cf[(size_t)row * N + col] = v;
                }
            }
        }
    }
}

// ------------------------------ log_softmax -------------------------------

__device__ inline float wred_max(float v) {
#pragma unroll
    for (int o = 32; o; o >>= 1) v = fmaxf(v, __shfl_xor(v, o));
    return v;
}
__device__ inline float wred_sum(float v) {
#pragma unroll
    for (int o = 32; o; o >>= 1) v += __shfl_xor(v, o);
    return v;
}

__global__ __launch_bounds__(256) void k_lsm(const float* __restrict__ in, float* __restrict__ out, int n) {
    int gw = (int)((blockIdx.x * blockDim.x + threadIdx.x) >> 6);
    int lane = threadIdx.x & 63;
    if (gw >= n) return;
    float v = (lane < 40) ? in[(size_t)gw * 40 + lane] : -INFINITY;
    float m = wred_max(v);
    float e = (lane < 40) ? __expf(v - m) : 0.f;
    float s = wred_sum(e);
    if (lane < 40) out[(size_t)gw * 40 + lane] = v - m - __logf(s);
}

// ------------------------------ host --------------------------------------

extern "C" void kernel_launch(void* const* d_in, const int* in_sizes, int n_in,
                              void* d_out, int out_size, void* d_ws, size_t ws_size,
                              hipStream_t stream) {
    const float* x   = (const float*)d_in[0];
    const int*   ei  = (const int*)d_in[1];
    const float* ea  = (const float*)d_in[2];
    const float* W1  = (const float*)d_in[3];  const float* b1  = (const float*)d_in[4];
    const float* W2  = (const float*)d_in[5];  const float* b2  = (const float*)d_in[6];
    const float* W3  = (const float*)d_in[7];  const float* b3  = (const float*)d_in[8];
    const float* fW1 = (const float*)d_in[9];  const float* fb1 = (const float*)d_in[10];
    const float* fW2 = (const float*)d_in[11]; const float* fb2 = (const float*)d_in[12];

    int n = in_sizes[0] / 64;
    int E = in_sizes[1] / 2;
    int Mp = ((n + 127) / 128) * 128;
    const int* src = ei;
    const int* dst = ei + E;
    float* out = (float*)d_out;

    char* p = (char*)d_ws;
    auto alloc = [&](size_t bytes) -> char* {
        char* r = p;
        p += (bytes + 255) & ~(size_t)255;
        return r;
    };
    float* deg      = (float*)alloc((size_t)n * 4);
    float* dinv     = (float*)alloc((size_t)n * 4);
    int*   cnt      = (int*)alloc((size_t)n * 4);
    int*   cursor   = (int*)alloc((size_t)n * 4);
    int*   rowptr   = (int*)alloc((size_t)(n + 1) * 4);
    int*   csr_src  = (int*)alloc((size_t)E * 4);
    float* csr_norm = (float*)alloc((size_t)E * 4);
    // weight planes (transposed, split)
    u16* W1Th = (u16*)alloc((size_t)128 * 64 * 2);   u16* W1Tl = (u16*)alloc((size_t)128 * 64 * 2);
    u16* W2Th = (u16*)alloc((size_t)256 * 128 * 2);  u16* W2Tl = (u16*)alloc((size_t)256 * 128 * 2);
    u16* W3Th = (u16*)alloc((size_t)512 * 256 * 2);  u16* W3Tl = (u16*)alloc((size_t)512 * 256 * 2);
    u16* F1Th = (u16*)alloc((size_t)512 * 512 * 2);  u16* F1Tl = (u16*)alloc((size_t)512 * 512 * 2);
    u16* F2Th = (u16*)alloc((size_t)128 * 512 * 2);  u16* F2Tl = (u16*)alloc((size_t)128 * 512 * 2);
    // activation planes
    u16* AGGh = (u16*)alloc((size_t)Mp * 256 * 2);   u16* AGGl = (u16*)alloc((size_t)Mp * 256 * 2);
    u16* HAh  = (u16*)alloc((size_t)Mp * 512 * 2);   u16* HAl  = (u16*)alloc((size_t)Mp * 512 * 2);
    u16* HBh  = (u16*)alloc((size_t)Mp * 512 * 2);   u16* HBl  = (u16*)alloc((size_t)Mp * 512 * 2);
    float* logits = (float*)AGGh;  // AGG dead after conv3's GEMM reads it

    const int tb = 256;
    int nBk = (n + tb - 1) / tb;
    int eB = (E + tb - 1) / tb;
    int waveB = (int)(((size_t)n * 64 + tb - 1) / tb);

    // graph prep
    k_init<<<nBk, tb, 0, stream>>>(deg, cnt, cursor, n);
    k_edge1<<<eB, tb, 0, stream>>>(src, dst, ea, deg, cnt, E);
    k_dinv<<<nBk, tb, 0, stream>>>(deg, dinv, n);
    k_scan<<<1, 1024, 0, stream>>>(cnt, rowptr, n);
    k_fill<<<eB, tb, 0, stream>>>(src, dst, ea, dinv, rowptr, cursor, csr_src, csr_norm, E);

    // weight prep (split + transpose, pad fc2 to 128 rows)
    auto wp = [&](const float* W, u16* Th, u16* Tl, int K, int N, int Np) {
        int tot = Np * K;
        k_wprep<<<(tot + tb - 1) / tb, tb, 0, stream>>>(W, Th, Tl, K, N, Np);
    };
    wp(W1, W1Th, W1Tl, 64, 128, 128);
    wp(W2, W2Th, W2Tl, 128, 256, 256);
    wp(W3, W3Th, W3Tl, 256, 512, 512);
    wp(fW1, F1Th, F1Tl, 512, 512, 512);
    wp(fW2, F2Th, F2Tl, 512, 40, 128);

    int mB = Mp / 128;
    auto mm = [&](const u16* ah, const u16* al, const u16* bth, const u16* btl, const float* bias,
                  u16* ch, u16* cl, float* cf, int N, int K, bool relu, bool split) {
        int nB2 = (N + 127) / 128;
        int nwg = mB * nB2;
        if (relu && split)
            k_mm<true, true><<<nwg, 256, 0, stream>>>(ah, al, bth, btl, bias, ch, cl, cf, n, N, K, nB2, nwg);
        else
            k_mm<false, false><<<nwg, 256, 0, stream>>>(ah, al, bth, btl, bias, ch, cl, cf, n, N, K, nB2, nwg);
    };

    // conv1: agg(x) -> @W1 relu -> HA[.,128]
    k_agg<64, true><<<waveB, tb, 0, stream>>>(x, nullptr, nullptr, dinv, rowptr, csr_src, csr_norm, AGGh, AGGl, n);
    mm(AGGh, AGGl, W1Th, W1Tl, b1, HAh, HAl, nullptr, 128, 64, true, true);
    // conv2: agg(HA) -> @W2 relu -> HB[.,256]
    k_agg<128, false><<<waveB, tb, 0, stream>>>(nullptr, HAh, HAl, dinv, rowptr, csr_src, csr_norm, AGGh, AGGl, n);
    mm(AGGh, AGGl, W2Th, W2Tl, b2, HBh, HBl, nullptr, 256, 128, true, true);
    // conv3: agg(HB) -> @W3 relu -> HA[.,512]
    k_agg<256, false><<<waveB, tb, 0, stream>>>(nullptr, HBh, HBl, dinv, rowptr, csr_src, csr_norm, AGGh, AGGl, n);
    mm(AGGh, AGGl, W3Th, W3Tl, b3, HAh, HAl, nullptr, 512, 256, true, true);
    // fc1: HA @ fW1 relu -> HB[.,512]
    mm(HAh, HAl, F1Th, F1Tl, fb1, HBh, HBl, nullptr, 512, 512, true, true);
    // fc2: HB @ fW2 -> logits f32 (reuses AGG space)
    mm(HBh, HBl, F2Th, F2Tl, fb2, nullptr, nullptr, logits, 40, 512, false, false);
    // log_softmax
    k_lsm<<<waveB, tb, 0, stream>>>(logits, out, n);
}

// Round 3
// 426.747 us; speedup vs baseline: 1.6793x; 1.3836x over previous
//
#include <hip/hip_runtime.h>
#include <cstdint>
#include <cstddef>

// ---------------------------------------------------------------------------
// GCN 3-conv + MLP head. FP16 single-product MFMA GEMMs (f32 accumulate),
// f16 activations, aggregate-before-linear (A(xW) == (Ax)W, Fin<Fout).
// Operand-swapped MFMA -> C^T fragment layout -> coalesced 8B epilogue stores.
// ---------------------------------------------------------------------------

typedef _Float16 f16;
typedef _Float16 half8 __attribute__((ext_vector_type(8)));
typedef _Float16 half4 __attribute__((ext_vector_type(4)));
typedef _Float16 half2v __attribute__((ext_vector_type(2)));
typedef float v4f __attribute__((ext_vector_type(4)));

__device__ inline void gload_lds16(const void* g, void* l) {
    __builtin_amdgcn_global_load_lds(
        (const __attribute__((address_space(1))) unsigned int*)g,
        (__attribute__((address_space(3))) unsigned int*)l, 16, 0, 0);
}

// ------------------------------ graph prep --------------------------------

__global__ __launch_bounds__(256) void k_init(float* deg, int* cnt, int* cursor, int n) {
    int i = blockIdx.x * blockDim.x + threadIdx.x;
    if (i < n) { deg[i] = 1.0f; cnt[i] = 0; cursor[i] = 0; }
}

__global__ __launch_bounds__(256) void k_edge1(const int* __restrict__ src, const int* __restrict__ dst,
                                               const float* __restrict__ ew,
                                               float* deg, int* cnt, int E) {
    int e = blockIdx.x * blockDim.x + threadIdx.x;
    if (e < E) {
        int d = dst[e];
        atomicAdd(&deg[d], ew[e]);
        atomicAdd(&cnt[d], 1);
    }
}

__global__ __launch_bounds__(256) void k_dinv(const float* __restrict__ deg, float* __restrict__ dinv, int n) {
    int i = blockIdx.x * blockDim.x + threadIdx.x;
    if (i < n) {
        float d = deg[i];
        float r = (d > 0.f) ? rsqrtf(d) : 0.f;
        r = r * (1.5f - 0.5f * d * r * r);  // Newton refine
        dinv[i] = r;
    }
}

__global__ __launch_bounds__(1024) void k_scan(const int* __restrict__ cnt, int* __restrict__ rowptr, int n) {
    __shared__ int s[1024];
    __shared__ int carry;
    int tid = threadIdx.x;
    if (tid == 0) carry = 0;
    __syncthreads();
    for (int base = 0; base < n; base += 1024) {
        int v = (base + tid < n) ? cnt[base + tid] : 0;
        s[tid] = v;
        __syncthreads();
        for (int off = 1; off < 1024; off <<= 1) {
            int t = (tid >= off) ? s[tid - off] : 0;
            __syncthreads();
            s[tid] += t;
            __syncthreads();
        }
        int incl = s[tid];
        int c = carry;
        if (base + tid < n) rowptr[base + tid] = c + incl - v;
        __syncthreads();
        if (tid == 0) carry = c + s[1023];
        __syncthreads();
    }
    if (tid == 0) rowptr[n] = carry;
}

__global__ __launch_bounds__(256) void k_fill(const int* __restrict__ src, const int* __restrict__ dst,
                                              const float* __restrict__ ew, const float* __restrict__ dinv,
                                              const int* __restrict__ rowptr, int* __restrict__ cursor,
                                              int* __restrict__ csr_src, float* __restrict__ csr_norm, int E) {
    int e = blockIdx.x * blockDim.x + threadIdx.x;
    if (e < E) {
        int d = dst[e], s = src[e];
        int p = atomicAdd(&cursor[d], 1);
        int idx = rowptr[d] + p;
        csr_src[idx] = s;
        csr_norm[idx] = dinv[s] * ew[e] * dinv[d];
    }
}

// Weight transpose: W[K,N] f32 -> WT[Np,K] f16 (rows >= N zeroed).
__global__ __launch_bounds__(256) void k_wprep(const float* __restrict__ W, f16* __restrict__ WT,
                                               int K, int N, int Np) {
    int i = blockIdx.x * blockDim.x + threadIdx.x;
    if (i >= Np * K) return;
    int nr = i / K, k = i % K;
    float v = (nr < N) ? W[(size_t)k * N + nr] : 0.f;
    WT[i] = (f16)v;
}

// ------------------------------ aggregation -------------------------------
// out[i,:] = dinv[i]^2*h[i,:] + sum_j norm_j*h[src_j,:]; f16 in/out, f32 acc.
template <int F, bool IN_F32>
__global__ __launch_bounds__(256) void k_agg(const float* __restrict__ hf, const f16* __restrict__ h,
                                             const float* __restrict__ dinv, const int* __restrict__ rowptr,
                                             const int* __restrict__ csr_src, const float* __restrict__ csr_norm,
                                             f16* __restrict__ o, int n) {
    constexpr int V = F / 64;
    int gw = (int)((blockIdx.x * blockDim.x + threadIdx.x) >> 6);
    int lane = threadIdx.x & 63;
    if (gw >= n) return;
    float di = dinv[gw], w0 = di * di;
    float acc[V];
#pragma unroll
    for (int v = 0; v < V; ++v) acc[v] = 0.f;

    auto gat = [&](size_t rowbase, float w) {
        if constexpr (IN_F32) {
            acc[0] += w * hf[rowbase + lane];
        } else if constexpr (V == 1) {
            acc[0] += w * (float)h[rowbase + lane];
        } else if constexpr (V == 2) {
            half2v x = *(const half2v*)(h + rowbase + lane * 2);
            acc[0] += w * (float)x[0];
            acc[1] += w * (float)x[1];
        } else {
            half4 x = *(const half4*)(h + rowbase + lane * 4);
            acc[0] += w * (float)x[0];
            acc[1] += w * (float)x[1];
            acc[2] += w * (float)x[2];
            acc[3] += w * (float)x[3];
        }
    };

    gat((size_t)gw * F, w0);
    int beg = rowptr[gw], end = rowptr[gw + 1];
    for (int j = beg; j < end; ++j) {
        gat((size_t)csr_src[j] * F, csr_norm[j]);
    }

    size_t ob = (size_t)gw * F + (size_t)lane * V;
    if constexpr (V == 1) {
        o[ob] = (f16)acc[0];
    } else if constexpr (V == 2) {
        half2v x = {(f16)acc[0], (f16)acc[1]};
        *(half2v*)(o + ob) = x;
    } else {
        half4 x = {(f16)acc[0], (f16)acc[1], (f16)acc[2], (f16)acc[3]};
        *(half4*)(o + ob) = x;
    }
}

// ------------------------------ MFMA GEMM ---------------------------------
// C[M,N] = act(A[M,K] @ B[K,N] + bias). A f16 row-major (padded rows ok),
// BT f16 [Np,K] (transposed weights). 128x128 tile, BK=64, 4 waves (2x2),
// mfma_f32_16x16x32_f16 with swapped operands -> D = C^T fragments: each
// lane holds 4 consecutive n at fixed m -> 8B coalesced stores.
// A staged to LDS via global_load_lds, XOR-swizzled (inverse-swz source,
// swz read), double-buffered, one barrier per k-step.
template <bool RELU, bool F16OUT>
__global__ __launch_bounds__(256) void k_mm(const f16* __restrict__ A, const f16* __restrict__ BT,
                                            const float* __restrict__ bias,
                                            f16* __restrict__ Ch, float* __restrict__ Cf,
                                            int M, int N, int K, int nB, int nwg) {
    __shared__ f16 lsA[2][128 * 64];

    // bijective XCD-aware block swizzle (m204)
    int wg = blockIdx.x;
    int q = nwg >> 3, r = nwg & 7;
    int xcd = wg & 7, lin = wg >> 3;
    int wgs = (xcd < r) ? (xcd * (q + 1) + lin) : (r * (q + 1) + (xcd - r) * q + lin);
    int bm = wgs / nB, bn = wgs % nB;

    int tid = threadIdx.x;
    int lane = tid & 63, wid = tid >> 6;
    int l16 = lane & 15, lhi = lane >> 4;
    int wm = (wid >> 1) * 64, wn = (wid & 1) * 64;
    int brow = bm * 128, bcol = bn * 128;

    v4f acc[4][4] = {};

    auto stage = [&](int buf, int k0) {
#pragma unroll
        for (int i = 0; i < 4; ++i) {
            int b = i * 4096 + tid * 16;         // byte offset in 16KB buffer
            int row = b >> 7;                     // LDS row (128B row stride)
            int s = ((b >> 4) & 7) ^ (row & 7);   // inverse-swizzled k-slot
            const f16* g = A + (size_t)(brow + row) * K + k0 + s * 8;
            gload_lds16(g, ((char*)&lsA[buf][0]) + b);
        }
    };

    int nk = K >> 6;
    stage(0, 0);
    for (int kt = 0; kt < nk; ++kt) {
        int cur = kt & 1;
        __syncthreads();  // drains vmcnt: buf[cur] ready; prev reads of buf[cur^1] done
        if (kt + 1 < nk) stage(cur ^ 1, (kt + 1) << 6);
        // B^T fragments ("A operand" after swap) straight from L2-resident weights
        half8 bf[2][4];
#pragma unroll
        for (int ks = 0; ks < 2; ++ks)
#pragma unroll
            for (int fn = 0; fn < 4; ++fn) {
                size_t off = (size_t)(bcol + wn + fn * 16 + l16) * K + (kt << 6) + ks * 32 + lhi * 8;
                bf[ks][fn] = *(const half8*)(BT + off);
            }
#pragma unroll
        for (int ks = 0; ks < 2; ++ks)
#pragma unroll
            for (int fm = 0; fm < 4; ++fm) {
                int row = wm + fm * 16 + l16;
                int sidx = (ks * 4 + lhi) ^ (row & 7);
                half8 af = *(const half8*)(&lsA[cur][0] + row * 64 + sidx * 8);
#pragma unroll
                for (int fn = 0; fn < 4; ++fn)
                    acc[fm][fn] = __builtin_amdgcn_mfma_f32_16x16x32_f16(bf[ks][fn], af, acc[fm][fn], 0, 0, 0);
            }
    }

    // epilogue: D = C^T frags: lane -> m = ...+l16 (col), n = ...+lhi*4+reg (row)
#pragma unroll
    for (int fm = 0; fm < 4; ++fm) {
        int m = brow + wm + fm * 16 + l16;
        if (m >= M) continue;
#pragma unroll
        for (int fn = 0; fn < 4; ++fn) {
            int nb = bcol + wn + fn * 16 + lhi * 4;
            if (F16OUT) {
                v4f bv = *(const v4f*)(bias + nb);
                v4f v = acc[fm][fn] + bv;
                if (RELU) {
#pragma unroll
                    for (int rr = 0; rr < 4; ++rr) v[rr] = fmaxf(v[rr], 0.f);
                }
                half4 hv = {(f16)v[0], (f16)v[1], (f16)v[2], (f16)v[3]};
                *(half4*)(Ch + (size_t)m * N + nb) = hv;
            } else {
#pragma unroll
                for (int rr = 0; rr < 4; ++rr) {
                    int nn = nb + rr;
                    if (nn < N) {
                        float v = acc[fm][fn][rr] + bias[nn];
                        if (RELU) v = fmaxf(v, 0.f);
                        Cf[(size_t)m * N + nn] = v;
                    }
                }
            }
        }
    }
}

// ------------------------------ log_softmax -------------------------------

__device__ inline float wred_max(float v) {
#pragma unroll
    for (int o = 32; o; o >>= 1) v = fmaxf(v, __shfl_xor(v, o));
    return v;
}
__device__ inline float wred_sum(float v) {
#pragma unroll
    for (int o = 32; o; o >>= 1) v += __shfl_xor(v, o);
    return v;
}

__global__ __launch_bounds__(256) void k_lsm(const float* __restrict__ in, float* __restrict__ out, int n) {
    int gw = (int)((blockIdx.x * blockDim.x + threadIdx.x) >> 6);
    int lane = threadIdx.x & 63;
    if (gw >= n) return;
    float v = (lane < 40) ? in[(size_t)gw * 40 + lane] : -INFINITY;
    float m = wred_max(v);
    float e = (lane < 40) ? __expf(v - m) : 0.f;
    float s = wred_sum(e);
    if (lane < 40) out[(size_t)gw * 40 + lane] = v - m - __logf(s);
}

// ------------------------------ host --------------------------------------

extern "C" void kernel_launch(void* const* d_in, const int* in_sizes, int n_in,
                              void* d_out, int out_size, void* d_ws, size_t ws_size,
                              hipStream_t stream) {
    const float* x   = (const float*)d_in[0];
    const int*   ei  = (const int*)d_in[1];
    const float* ea  = (const float*)d_in[2];
    const float* W1  = (const float*)d_in[3];  const float* b1  = (const float*)d_in[4];
    const float* W2  = (const float*)d_in[5];  const float* b2  = (const float*)d_in[6];
    const float* W3  = (const float*)d_in[7];  const float* b3  = (const float*)d_in[8];
    const float* fW1 = (const float*)d_in[9];  const float* fb1 = (const float*)d_in[10];
    const float* fW2 = (const float*)d_in[11]; const float* fb2 = (const float*)d_in[12];

    int n = in_sizes[0] / 64;
    int E = in_sizes[1] / 2;
    int Mp = ((n + 127) / 128) * 128;
    const int* src = ei;
    const int* dst = ei + E;
    float* out = (float*)d_out;

    char* p = (char*)d_ws;
    auto alloc = [&](size_t bytes) -> char* {
        char* r = p;
        p += (bytes + 255) & ~(size_t)255;
        return r;
    };
    float* deg      = (float*)alloc((size_t)n * 4);
    float* dinv     = (float*)alloc((size_t)n * 4);
    int*   cnt      = (int*)alloc((size_t)n * 4);
    int*   cursor   = (int*)alloc((size_t)n * 4);
    int*   rowptr   = (int*)alloc((size_t)(n + 1) * 4);
    int*   csr_src  = (int*)alloc((size_t)E * 4);
    float* csr_norm = (float*)alloc((size_t)E * 4);
    f16* W1T = (f16*)alloc((size_t)128 * 64 * 2);
    f16* W2T = (f16*)alloc((size_t)256 * 128 * 2);
    f16* W3T = (f16*)alloc((size_t)512 * 256 * 2);
    f16* F1T = (f16*)alloc((size_t)512 * 512 * 2);
    f16* F2T = (f16*)alloc((size_t)128 * 512 * 2);
    f16* AGG = (f16*)alloc((size_t)Mp * 256 * 2);
    f16* HA  = (f16*)alloc((size_t)Mp * 512 * 2);
    f16* HB  = (f16*)alloc((size_t)Mp * 512 * 2);
    float* logits = (float*)alloc((size_t)Mp * 40 * 4);

    const int tb = 256;
    int nBk = (n + tb - 1) / tb;
    int eB = (E + tb - 1) / tb;
    int waveB = (int)(((size_t)n * 64 + tb - 1) / tb);

    // graph prep
    k_init<<<nBk, tb, 0, stream>>>(deg, cnt, cursor, n);
    k_edge1<<<eB, tb, 0, stream>>>(src, dst, ea, deg, cnt, E);
    k_dinv<<<nBk, tb, 0, stream>>>(deg, dinv, n);
    k_scan<<<1, 1024, 0, stream>>>(cnt, rowptr, n);
    k_fill<<<eB, tb, 0, stream>>>(src, dst, ea, dinv, rowptr, cursor, csr_src, csr_norm, E);

    // weight prep (transpose to [Np,K] f16)
    auto wp = [&](const float* W, f16* WT, int K, int N, int Np) {
        int tot = Np * K;
        k_wprep<<<(tot + tb - 1) / tb, tb, 0, stream>>>(W, WT, K, N, Np);
    };
    wp(W1, W1T, 64, 128, 128);
    wp(W2, W2T, 128, 256, 256);
    wp(W3, W3T, 256, 512, 512);
    wp(fW1, F1T, 512, 512, 512);
    wp(fW2, F2T, 512, 40, 128);

    int mB = Mp / 128;
    auto mm = [&](const f16* a, const f16* bt, const float* bias, f16* ch, float* cf,
                  int N, int Np, int K, bool relu_f16) {
        int nB2 = Np / 128;
        int nwg = mB * nB2;
        if (relu_f16)
            k_mm<true, true><<<nwg, 256, 0, stream>>>(a, bt, bias, ch, cf, n, N, K, nB2, nwg);
        else
            k_mm<false, false><<<nwg, 256, 0, stream>>>(a, bt, bias, ch, cf, n, N, K, nB2, nwg);
    };

    // conv1: agg(x)[.,64] -> @W1 relu -> HA[.,128]
    k_agg<64, true><<<waveB, tb, 0, stream>>>(x, nullptr, dinv, rowptr, csr_src, csr_norm, AGG, n);
    mm(AGG, W1T, b1, HA, nullptr, 128, 128, 64, true);
    // conv2: agg(HA)[.,128] -> @W2 relu -> HB[.,256]
    k_agg<128, false><<<waveB, tb, 0, stream>>>(nullptr, HA, dinv, rowptr, csr_src, csr_norm, AGG, n);
    mm(AGG, W2T, b2, HB, nullptr, 256, 256, 128, true);
    // conv3: agg(HB)[.,256] -> @W3 relu -> HA[.,512]
    k_agg<256, false><<<waveB, tb, 0, stream>>>(nullptr, HB, dinv, rowptr, csr_src, csr_norm, AGG, n);
    mm(AGG, W3T, b3, HA, nullptr, 512, 512, 256, true);
    // fc1: HA @ fW1 relu -> HB[.,512]
    mm(HA, F1T, fb1, HB, nullptr, 512, 512, 512, true);
    // fc2: HB @ fW2 -> logits f32 [.,40]
    mm(HB, F2T, fb2, nullptr, logits, 40, 128, 512, false);
    // log_softmax
    k_lsm<<<waveB, tb, 0, stream>>>(logits, out, n);
}

// Round 4
// 343.079 us; speedup vs baseline: 2.0888x; 1.2439x over previous
//
#include <hip/hip_runtime.h>
#include <cstdint>
#include <cstddef>

// ---------------------------------------------------------------------------
// GCN 3-conv + MLP head. FP16 single-product MFMA GEMMs (f32 accumulate),
// f16 activations, aggregate-before-linear (A(xW) == (Ax)W, Fin<Fout).
// Multi-node-per-wave gather aggregation (16B/lane, 2-edge unrolled).
// ---------------------------------------------------------------------------

typedef _Float16 f16;
typedef _Float16 half8 __attribute__((ext_vector_type(8)));
typedef _Float16 half4 __attribute__((ext_vector_type(4)));
typedef float v4f __attribute__((ext_vector_type(4)));

__device__ inline void gload_lds16(const void* g, void* l) {
    __builtin_amdgcn_global_load_lds(
        (const __attribute__((address_space(1))) unsigned int*)g,
        (__attribute__((address_space(3))) unsigned int*)l, 16, 0, 0);
}

// ------------------------------ graph prep --------------------------------

__global__ __launch_bounds__(256) void k_init(float* deg, int* cnt, int* cursor, int n) {
    int i = blockIdx.x * blockDim.x + threadIdx.x;
    if (i < n) { deg[i] = 1.0f; cnt[i] = 0; cursor[i] = 0; }
}

__global__ __launch_bounds__(256) void k_edge1(const int* __restrict__ src, const int* __restrict__ dst,
                                               const float* __restrict__ ew,
                                               float* deg, int* cnt, int E) {
    int e = blockIdx.x * blockDim.x + threadIdx.x;
    if (e < E) {
        int d = dst[e];
        atomicAdd(&deg[d], ew[e]);
        atomicAdd(&cnt[d], 1);
    }
}

__global__ __launch_bounds__(256) void k_dinv(const float* __restrict__ deg, float* __restrict__ dinv, int n) {
    int i = blockIdx.x * blockDim.x + threadIdx.x;
    if (i < n) {
        float d = deg[i];
        float r = (d > 0.f) ? rsqrtf(d) : 0.f;
        r = r * (1.5f - 0.5f * d * r * r);  // Newton refine
        dinv[i] = r;
    }
}

__global__ __launch_bounds__(1024) void k_scan(const int* __restrict__ cnt, int* __restrict__ rowptr, int n) {
    __shared__ int s[1024];
    __shared__ int carry;
    int tid = threadIdx.x;
    if (tid == 0) carry = 0;
    __syncthreads();
    for (int base = 0; base < n; base += 1024) {
        int v = (base + tid < n) ? cnt[base + tid] : 0;
        s[tid] = v;
        __syncthreads();
        for (int off = 1; off < 1024; off <<= 1) {
            int t = (tid >= off) ? s[tid - off] : 0;
            __syncthreads();
            s[tid] += t;
            __syncthreads();
        }
        int incl = s[tid];
        int c = carry;
        if (base + tid < n) rowptr[base + tid] = c + incl - v;
        __syncthreads();
        if (tid == 0) carry = c + s[1023];
        __syncthreads();
    }
    if (tid == 0) rowptr[n] = carry;
}

__global__ __launch_bounds__(256) void k_fill(const int* __restrict__ src, const int* __restrict__ dst,
                                              const float* __restrict__ ew, const float* __restrict__ dinv,
                                              const int* __restrict__ rowptr, int* __restrict__ cursor,
                                              int* __restrict__ csr_src, float* __restrict__ csr_norm, int E) {
    int e = blockIdx.x * blockDim.x + threadIdx.x;
    if (e < E) {
        int d = dst[e], s = src[e];
        int p = atomicAdd(&cursor[d], 1);
        int idx = rowptr[d] + p;
        csr_src[idx] = s;
        csr_norm[idx] = dinv[s] * ew[e] * dinv[d];
    }
}

// Weight transpose: W[K,N] f32 -> WT[Np,K] f16 (rows >= N zeroed).
__global__ __launch_bounds__(256) void k_wprep(const float* __restrict__ W, f16* __restrict__ WT,
                                               int K, int N, int Np) {
    int i = blockIdx.x * blockDim.x + threadIdx.x;
    if (i >= Np * K) return;
    int nr = i / K, k = i % K;
    float v = (nr < N) ? W[(size_t)k * N + nr] : 0.f;
    WT[i] = (f16)v;
}

// ------------------------------ aggregation -------------------------------
// out[i,:] = dinv[i]^2*h[i,:] + sum_j norm_j*h[src_j,:]; f16 out, f32 acc.
// 16B per lane; LPN lanes cover one node's row; NPW nodes per wave for MLP.
template <int F, bool IN_F32>
__global__ __launch_bounds__(256) void k_agg(const float* __restrict__ hf, const f16* __restrict__ h,
                                             const float* __restrict__ dinv, const int* __restrict__ rowptr,
                                             const int* __restrict__ csr_src, const float* __restrict__ csr_norm,
                                             f16* __restrict__ o, int n) {
    constexpr int EL = IN_F32 ? 4 : 8;   // elems per lane = 16B
    constexpr int LPN = F / EL;          // lanes per node
    constexpr int NPW = 64 / LPN;        // nodes per wave
    int wave = (int)((blockIdx.x * (unsigned)blockDim.x + threadIdx.x) >> 6);
    int lane = threadIdx.x & 63;
    int grp = lane / LPN, lin = lane % LPN;
    int node = wave * NPW + grp;
    if (node >= n) return;
    float di = dinv[node], w0 = di * di;
    float acc[EL];
#pragma unroll
    for (int i = 0; i < EL; ++i) acc[i] = 0.f;

    auto gat = [&](int s, float w) {
        if constexpr (IN_F32) {
            float4 x = *(const float4*)(hf + (size_t)s * F + lin * 4);
            acc[0] += w * x.x; acc[1] += w * x.y; acc[2] += w * x.z; acc[3] += w * x.w;
        } else {
            half8 x = *(const half8*)(h + (size_t)s * F + lin * 8);
#pragma unroll
            for (int i = 0; i < 8; ++i) acc[i] += w * (float)x[i];
        }
    };

    gat(node, w0);
    int beg = rowptr[node], end = rowptr[node + 1];
    int j = beg;
    for (; j + 1 < end; j += 2) {  // 2-edge unroll: two independent gathers in flight
        int s0 = csr_src[j], s1 = csr_src[j + 1];
        float u0 = csr_norm[j], u1 = csr_norm[j + 1];
        gat(s0, u0);
        gat(s1, u1);
    }
    if (j < end) gat(csr_src[j], csr_norm[j]);

    size_t ob = (size_t)node * F + (size_t)lin * EL;
    if constexpr (EL == 4) {
        half4 v = {(f16)acc[0], (f16)acc[1], (f16)acc[2], (f16)acc[3]};
        *(half4*)(o + ob) = v;
    } else {
        half8 v;
#pragma unroll
        for (int i = 0; i < 8; ++i) v[i] = (f16)acc[i];
        *(half8*)(o + ob) = v;
    }
}

// ------------------------------ MFMA GEMM ---------------------------------
// C[M,N] = act(A[M,K] @ B[K,N] + bias). A f16 row-major, BT f16 [Np,K].
// 128x128 tile, BK=64, 4 waves (2x2), mfma_f32_16x16x32_f16 operand-swapped
// (D = C^T fragments -> coalesced 8B stores). A staged via global_load_lds
// (XOR-swizzled both sides), double-buffered; B-frag loads issued BEFORE the
// next-tile stage so the B waitcnt leaves the staging loads in flight.
template <bool RELU, bool F16OUT>
__global__ __launch_bounds__(256) void k_mm(const f16* __restrict__ A, const f16* __restrict__ BT,
                                            const float* __restrict__ bias,
                                            f16* __restrict__ Ch, float* __restrict__ Cf,
                                            int M, int N, int K, int nB, int nwg) {
    __shared__ f16 lsA[2][128 * 64];

    // bijective XCD-aware block swizzle (m204)
    int wg = blockIdx.x;
    int q = nwg >> 3, r = nwg & 7;
    int xcd = wg & 7, lin = wg >> 3;
    int wgs = (xcd < r) ? (xcd * (q + 1) + lin) : (r * (q + 1) + (xcd - r) * q + lin);
    int bm = wgs / nB, bn = wgs % nB;

    int tid = threadIdx.x;
    int lane = tid & 63, wid = tid >> 6;
    int l16 = lane & 15, lhi = lane >> 4;
    int wm = (wid >> 1) * 64, wn = (wid & 1) * 64;
    int brow = bm * 128, bcol = bn * 128;

    v4f acc[4][4] = {};

    auto stage = [&](int buf, int k0) {
#pragma unroll
        for (int i = 0; i < 4; ++i) {
            int b = i * 4096 + tid * 16;          // byte offset in 16KB buffer
            int row = b >> 7;                     // LDS row (128B row stride)
            int s = ((b >> 4) & 7) ^ (row & 7);   // inverse-swizzled k-slot
            const f16* g = A + (size_t)(brow + row) * K + k0 + s * 8;
            gload_lds16(g, ((char*)&lsA[buf][0]) + b);
        }
    };

    int nk = K >> 6;
    stage(0, 0);
    for (int kt = 0; kt < nk; ++kt) {
        int cur = kt & 1;
        __syncthreads();  // buf[cur] staged; all waves' prior LDS reads done
        // B^T fragments first (independent of LDS), so their waitcnt does not
        // force the next stage's global_load_lds to drain.
        half8 bf[2][4];
#pragma unroll
        for (int ks = 0; ks < 2; ++ks)
#pragma unroll
            for (int fn = 0; fn < 4; ++fn) {
                size_t off = (size_t)(bcol + wn + fn * 16 + l16) * K + (kt << 6) + ks * 32 + lhi * 8;
                bf[ks][fn] = *(const half8*)(BT + off);
            }
        if (kt + 1 < nk) stage(cur ^ 1, (kt + 1) << 6);
#pragma unroll
        for (int ks = 0; ks < 2; ++ks)
#pragma unroll
            for (int fm = 0; fm < 4; ++fm) {
                int row = wm + fm * 16 + l16;
                int sidx = (ks * 4 + lhi) ^ (row & 7);
                half8 af = *(const half8*)(&lsA[cur][0] + row * 64 + sidx * 8);
#pragma unroll
                for (int fn = 0; fn < 4; ++fn)
                    acc[fm][fn] = __builtin_amdgcn_mfma_f32_16x16x32_f16(bf[ks][fn], af, acc[fm][fn], 0, 0, 0);
            }
    }

    // epilogue: C^T frags: m = ...+l16, n-block = ...+lhi*4 (4 consecutive n)
#pragma unroll
    for (int fm = 0; fm < 4; ++fm) {
        int m = brow + wm + fm * 16 + l16;
        if (m >= M) continue;
#pragma unroll
        for (int fn = 0; fn < 4; ++fn) {
            int nb = bcol + wn + fn * 16 + lhi * 4;
            if (F16OUT) {
                v4f bv = *(const v4f*)(bias + nb);
                v4f v = acc[fm][fn] + bv;
                if (RELU) {
#pragma unroll
                    for (int rr = 0; rr < 4; ++rr) v[rr] = fmaxf(v[rr], 0.f);
                }
                half4 hv = {(f16)v[0], (f16)v[1], (f16)v[2], (f16)v[3]};
                *(half4*)(Ch + (size_t)m * N + nb) = hv;
            } else {
#pragma unroll
                for (int rr = 0; rr < 4; ++rr) {
                    int nn = nb + rr;
                    if (nn < N) {
                        float v = acc[fm][fn][rr] + bias[nn];
                        if (RELU) v = fmaxf(v, 0.f);
                        Cf[(size_t)m * N + nn] = v;
                    }
                }
            }
        }
    }
}

// ------------------------------ log_softmax -------------------------------

__device__ inline float wred_max(float v) {
#pragma unroll
    for (int o = 32; o; o >>= 1) v = fmaxf(v, __shfl_xor(v, o));
    return v;
}
__device__ inline float wred_sum(float v) {
#pragma unroll
    for (int o = 32; o; o >>= 1) v += __shfl_xor(v, o);
    return v;
}

__global__ __launch_bounds__(256) void k_lsm(const float* __restrict__ in, float* __restrict__ out, int n) {
    int gw = (int)((blockIdx.x * blockDim.x + threadIdx.x) >> 6);
    int lane = threadIdx.x & 63;
    if (gw >= n) return;
    float v = (lane < 40) ? in[(size_t)gw * 40 + lane] : -INFINITY;
    float m = wred_max(v);
    float e = (lane < 40) ? __expf(v - m) : 0.f;
    float s = wred_sum(e);
    if (lane < 40) out[(size_t)gw * 40 + lane] = v - m - __logf(s);
}

// ------------------------------ host --------------------------------------

extern "C" void kernel_launch(void* const* d_in, const int* in_sizes, int n_in,
                              void* d_out, int out_size, void* d_ws, size_t ws_size,
                              hipStream_t stream) {
    const float* x   = (const float*)d_in[0];
    const int*   ei  = (const int*)d_in[1];
    const float* ea  = (const float*)d_in[2];
    const float* W1  = (const float*)d_in[3];  const float* b1  = (const float*)d_in[4];
    const float* W2  = (const float*)d_in[5];  const float* b2  = (const float*)d_in[6];
    const float* W3  = (const float*)d_in[7];  const float* b3  = (const float*)d_in[8];
    const float* fW1 = (const float*)d_in[9];  const float* fb1 = (const float*)d_in[10];
    const float* fW2 = (const float*)d_in[11]; const float* fb2 = (const float*)d_in[12];

    int n = in_sizes[0] / 64;
    int E = in_sizes[1] / 2;
    int Mp = ((n + 127) / 128) * 128;
    const int* src = ei;
    const int* dst = ei + E;
    float* out = (float*)d_out;

    char* p = (char*)d_ws;
    auto alloc = [&](size_t bytes) -> char* {
        char* r = p;
        p += (bytes + 255) & ~(size_t)255;
        return r;
    };
    float* deg      = (float*)alloc((size_t)n * 4);
    float* dinv     = (float*)alloc((size_t)n * 4);
    int*   cnt      = (int*)alloc((size_t)n * 4);
    int*   cursor   = (int*)alloc((size_t)n * 4);
    int*   rowptr   = (int*)alloc((size_t)(n + 1) * 4);
    int*   csr_src  = (int*)alloc((size_t)E * 4);
    float* csr_norm = (float*)alloc((size_t)E * 4);
    f16* W1T = (f16*)alloc((size_t)128 * 64 * 2);
    f16* W2T = (f16*)alloc((size_t)256 * 128 * 2);
    f16* W3T = (f16*)alloc((size_t)512 * 256 * 2);
    f16* F1T = (f16*)alloc((size_t)512 * 512 * 2);
    f16* F2T = (f16*)alloc((size_t)128 * 512 * 2);
    f16* AGG = (f16*)alloc((size_t)Mp * 256 * 2);
    f16* HA  = (f16*)alloc((size_t)Mp * 512 * 2);
    f16* HB  = (f16*)alloc((size_t)Mp * 512 * 2);
    float* logits = (float*)alloc((size_t)Mp * 40 * 4);

    const int tb = 256;
    int nBk = (n + tb - 1) / tb;
    int eB = (E + tb - 1) / tb;
    int waveB = (int)(((size_t)n * 64 + tb - 1) / tb);
    auto aggB = [&](int npw) {
        long waves = (n + npw - 1) / npw;
        return (int)((waves * 64 + tb - 1) / tb);
    };

    // graph prep
    k_init<<<nBk, tb, 0, stream>>>(deg, cnt, cursor, n);
    k_edge1<<<eB, tb, 0, stream>>>(src, dst, ea, deg, cnt, E);
    k_dinv<<<nBk, tb, 0, stream>>>(deg, dinv, n);
    k_scan<<<1, 1024, 0, stream>>>(cnt, rowptr, n);
    k_fill<<<eB, tb, 0, stream>>>(src, dst, ea, dinv, rowptr, cursor, csr_src, csr_norm, E);

    // weight prep (transpose to [Np,K] f16)
    auto wp = [&](const float* W, f16* WT, int K, int N, int Np) {
        int tot = Np * K;
        k_wprep<<<(tot + tb - 1) / tb, tb, 0, stream>>>(W, WT, K, N, Np);
    };
    wp(W1, W1T, 64, 128, 128);
    wp(W2, W2T, 128, 256, 256);
    wp(W3, W3T, 256, 512, 512);
    wp(fW1, F1T, 512, 512, 512);
    wp(fW2, F2T, 512, 40, 128);

    int mB = Mp / 128;
    auto mm = [&](const f16* a, const f16* bt, const float* bias, f16* ch, float* cf,
                  int N, int Np, int K, bool relu_f16) {
        int nB2 = Np / 128;
        int nwg = mB * nB2;
        if (relu_f16)
            k_mm<true, true><<<nwg, 256, 0, stream>>>(a, bt, bias, ch, cf, n, N, K, nB2, nwg);
        else
            k_mm<false, false><<<nwg, 256, 0, stream>>>(a, bt, bias, ch, cf, n, N, K, nB2, nwg);
    };

    // conv1: agg(x)[.,64] -> @W1 relu -> HA[.,128]
    k_agg<64, true><<<aggB(4), tb, 0, stream>>>(x, nullptr, dinv, rowptr, csr_src, csr_norm, AGG, n);
    mm(AGG, W1T, b1, HA, nullptr, 128, 128, 64, true);
    // conv2: agg(HA)[.,128] -> @W2 relu -> HB[.,256]
    k_agg<128, false><<<aggB(4), tb, 0, stream>>>(nullptr, HA, dinv, rowptr, csr_src, csr_norm, AGG, n);
    mm(AGG, W2T, b2, HB, nullptr, 256, 256, 128, true);
    // conv3: agg(HB)[.,256] -> @W3 relu -> HA[.,512]
    k_agg<256, false><<<aggB(2), tb, 0, stream>>>(nullptr, HB, dinv, rowptr, csr_src, csr_norm, AGG, n);
    mm(AGG, W3T, b3, HA, nullptr, 512, 512, 256, true);
    // fc1: HA @ fW1 relu -> HB[.,512]
    mm(HA, F1T, fb1, HB, nullptr, 512, 512, 512, true);
    // fc2: HB @ fW2 -> logits f32 [.,40]
    mm(HB, F2T, fb2, nullptr, logits, 40, 128, 512, false);
    // log_softmax
    k_lsm<<<waveB, tb, 0, stream>>>(logits, out, n);
}

// Round 5
// 288.133 us; speedup vs baseline: 2.4871x; 1.1907x over previous
//
#include <hip/hip_runtime.h>
#include <cstdint>
#include <cstddef>

// ---------------------------------------------------------------------------
// GCN 3-conv + MLP head. FP16 single-product MFMA GEMMs (f32 accumulate),
// f16 activations, aggregate-before-linear (A(xW) == (Ax)W, Fin<Fout).
// Multi-node-per-wave gather aggregation; 3-phase hierarchical CSR scan.
// ---------------------------------------------------------------------------

typedef _Float16 f16;
typedef _Float16 half8 __attribute__((ext_vector_type(8)));
typedef _Float16 half4 __attribute__((ext_vector_type(4)));
typedef float v4f __attribute__((ext_vector_type(4)));

__device__ inline void gload_lds16(const void* g, void* l) {
    __builtin_amdgcn_global_load_lds(
        (const __attribute__((address_space(1))) unsigned int*)g,
        (__attribute__((address_space(3))) unsigned int*)l, 16, 0, 0);
}

// ------------------------------ graph prep --------------------------------

__global__ __launch_bounds__(256) void k_init(float* deg, int* cnt, int* cursor, int n) {
    int i = blockIdx.x * blockDim.x + threadIdx.x;
    if (i < n) { deg[i] = 1.0f; cnt[i] = 0; cursor[i] = 0; }
}

__global__ __launch_bounds__(256) void k_edge1(const int* __restrict__ src, const int* __restrict__ dst,
                                               const float* __restrict__ ew,
                                               float* deg, int* cnt, int E) {
    int e = blockIdx.x * blockDim.x + threadIdx.x;
    if (e < E) {
        int d = dst[e];
        atomicAdd(&deg[d], ew[e]);
        atomicAdd(&cnt[d], 1);
    }
}

__global__ __launch_bounds__(256) void k_dinv(const float* __restrict__ deg, float* __restrict__ dinv, int n) {
    int i = blockIdx.x * blockDim.x + threadIdx.x;
    if (i < n) {
        float d = deg[i];
        float r = (d > 0.f) ? rsqrtf(d) : 0.f;
        r = r * (1.5f - 0.5f * d * r * r);  // Newton refine
        dinv[i] = r;
    }
}

// 256-thread inclusive block scan (shfl wave scan + LDS wave offsets).
__device__ inline int block_scan_incl(int v) {
    __shared__ int ws[4];
    int lane = threadIdx.x & 63, w = threadIdx.x >> 6;
#pragma unroll
    for (int off = 1; off < 64; off <<= 1) {
        int t = __shfl_up(v, off);
        if (lane >= off) v += t;
    }
    if (lane == 63) ws[w] = v;
    __syncthreads();
    int add = 0;
#pragma unroll
    for (int i = 0; i < 4; ++i) add += (i < w) ? ws[i] : 0;
    __syncthreads();  // ws reusable by caller's next invocation
    return v + add;
}

// phase 1: per-block (256 elems) sums of cnt -> bsum
__global__ __launch_bounds__(256) void k_scan1(const int* __restrict__ cnt, int* __restrict__ bsum, int n) {
    int i = blockIdx.x * 256 + threadIdx.x;
    int v = (i < n) ? cnt[i] : 0;
#pragma unroll
    for (int o = 32; o; o >>= 1) v += __shfl_xor(v, o);
    __shared__ int s[4];
    if ((threadIdx.x & 63) == 0) s[threadIdx.x >> 6] = v;
    __syncthreads();
    if (threadIdx.x == 0) bsum[blockIdx.x] = s[0] + s[1] + s[2] + s[3];
}

// phase 2: exclusive scan of block sums (single block) + total -> rowptr[n]
__global__ __launch_bounds__(256) void k_scan2(const int* __restrict__ bsum, int* __restrict__ boff,
                                               int* __restrict__ rowptr_last, int nb) {
    __shared__ int carry;
    if (threadIdx.x == 0) carry = 0;
    __syncthreads();
    for (int base = 0; base < nb; base += 256) {
        int i = base + threadIdx.x;
        int v = (i < nb) ? bsum[i] : 0;
        int incl = block_scan_incl(v);
        int c = carry;
        if (i < nb) boff[i] = c + incl - v;
        __syncthreads();
        if (threadIdx.x == 255) carry = c + incl;
        __syncthreads();
    }
    if (threadIdx.x == 0) *rowptr_last = carry;
}

// phase 3: local exclusive scan + block offset -> rowptr[0..n)
__global__ __launch_bounds__(256) void k_scan3(const int* __restrict__ cnt, const int* __restrict__ boff,
                                               int* __restrict__ rowptr, int n) {
    int i = blockIdx.x * 256 + threadIdx.x;
    int v = (i < n) ? cnt[i] : 0;
    int incl = block_scan_incl(v);
    if (i < n) rowptr[i] = boff[blockIdx.x] + incl - v;
}

__global__ __launch_bounds__(256) void k_fill(const int* __restrict__ src, const int* __restrict__ dst,
                                              const float* __restrict__ ew, const float* __restrict__ dinv,
                                              const int* __restrict__ rowptr, int* __restrict__ cursor,
                                              int* __restrict__ csr_src, float* __restrict__ csr_norm, int E) {
    int e = blockIdx.x * blockDim.x + threadIdx.x;
    if (e < E) {
        int d = dst[e], s = src[e];
        int p = atomicAdd(&cursor[d], 1);
        int idx = rowptr[d] + p;
        csr_src[idx] = s;
        csr_norm[idx] = dinv[s] * ew[e] * dinv[d];
    }
}

// x f32 -> f16, 4 elems/thread
__global__ __launch_bounds__(256) void k_xcast(const float* __restrict__ x, f16* __restrict__ xh, int total4) {
    int i = blockIdx.x * blockDim.x + threadIdx.x;
    if (i < total4) {
        float4 v = *(const float4*)(x + (size_t)i * 4);
        half4 h = {(f16)v.x, (f16)v.y, (f16)v.z, (f16)v.w};
        *(half4*)(xh + (size_t)i * 4) = h;
    }
}

// fused weight prep: 5 segments, W[K,N] f32 -> WT[Np,K] f16 (rows >= N zeroed)
struct WPrepArgs {
    const float* W[5];
    f16* WT[5];
    int lgK[5];   // K = 1 << lgK
    int N[5];     // true N (stride of W rows, col guard)
    int off[6];   // prefix offsets of Np*K
};
__global__ __launch_bounds__(256) void k_wprep_all(WPrepArgs a) {
    int i = blockIdx.x * 256 + threadIdx.x;
#pragma unroll
    for (int s = 0; s < 5; ++s) {
        if (i >= a.off[s] && i < a.off[s + 1]) {
            int li = i - a.off[s];
            int K = 1 << a.lgK[s];
            int nr = li >> a.lgK[s], k = li & (K - 1);
            float v = (nr < a.N[s]) ? a.W[s][(size_t)k * a.N[s] + nr] : 0.f;
            a.WT[s][li] = (f16)v;
        }
    }
}

// ------------------------------ aggregation -------------------------------
// out[i,:] = dinv[i]^2*h[i,:] + sum_j norm_j*h[src_j,:]; f16 in/out, f32 acc.
// 8 f16 (16B) per lane; LPN lanes per node; NPW nodes per wave.
template <int F>
__global__ __launch_bounds__(256) void k_agg(const f16* __restrict__ h,
                                             const float* __restrict__ dinv, const int* __restrict__ rowptr,
                                             const int* __restrict__ csr_src, const float* __restrict__ csr_norm,
                                             f16* __restrict__ o, int n) {
    constexpr int LPN = F / 8;           // lanes per node
    constexpr int NPW = 64 / LPN;        // nodes per wave
    int wave = (int)((blockIdx.x * (unsigned)blockDim.x + threadIdx.x) >> 6);
    int lane = threadIdx.x & 63;
    int grp = lane / LPN, lin = lane % LPN;
    int node = wave * NPW + grp;
    if (node >= n) return;
    float di = dinv[node], w0 = di * di;
    float acc[8];
#pragma unroll
    for (int i = 0; i < 8; ++i) acc[i] = 0.f;

    auto gat = [&](int s, float w) {
        half8 x = *(const half8*)(h + (size_t)s * F + lin * 8);
#pragma unroll
        for (int i = 0; i < 8; ++i) acc[i] += w * (float)x[i];
    };

    gat(node, w0);
    int beg = rowptr[node], end = rowptr[node + 1];
    int j = beg;
    for (; j + 1 < end; j += 2) {  // 2 independent gathers in flight
        int s0 = csr_src[j], s1 = csr_src[j + 1];
        float u0 = csr_norm[j], u1 = csr_norm[j + 1];
        gat(s0, u0);
        gat(s1, u1);
    }
    if (j < end) gat(csr_src[j], csr_norm[j]);

    half8 v;
#pragma unroll
    for (int i = 0; i < 8; ++i) v[i] = (f16)acc[i];
    *(half8*)(o + (size_t)node * F + (size_t)lin * 8) = v;
}

// ------------------------------ MFMA GEMM ---------------------------------
// C[M,N] = act(A[M,K] @ B[K,N] + bias). A f16 row-major, BT f16 [Np,K].
// 128x128 tile, BK=64, 4 waves (2x2), mfma_f32_16x16x32_f16 operand-swapped
// (D = C^T fragments -> coalesced 8B stores). A staged via global_load_lds
// (XOR-swizzled both sides), double-buffered; B-frag loads issued before the
// next-tile stage so their waitcnt leaves the staging loads in flight.
template <bool RELU, bool F16OUT>
__global__ __launch_bounds__(256) void k_mm(const f16* __restrict__ A, const f16* __restrict__ BT,
                                            const float* __restrict__ bias,
                                            f16* __restrict__ Ch, float* __restrict__ Cf,
                                            int M, int N, int K, int nB, int nwg) {
    __shared__ f16 lsA[2][128 * 64];

    // bijective XCD-aware block swizzle (m204)
    int wg = blockIdx.x;
    int q = nwg >> 3, r = nwg & 7;
    int xcd = wg & 7, lin = wg >> 3;
    int wgs = (xcd < r) ? (xcd * (q + 1) + lin) : (r * (q + 1) + (xcd - r) * q + lin);
    int bm = wgs / nB, bn = wgs % nB;

    int tid = threadIdx.x;
    int lane = tid & 63, wid = tid >> 6;
    int l16 = lane & 15, lhi = lane >> 4;
    int wm = (wid >> 1) * 64, wn = (wid & 1) * 64;
    int brow = bm * 128, bcol = bn * 128;

    v4f acc[4][4] = {};

    auto stage = [&](int buf, int k0) {
#pragma unroll
        for (int i = 0; i < 4; ++i) {
            int b = i * 4096 + tid * 16;          // byte offset in 16KB buffer
            int row = b >> 7;                     // LDS row (128B row stride)
            int s = ((b >> 4) & 7) ^ (row & 7);   // inverse-swizzled k-slot
            const f16* g = A + (size_t)(brow + row) * K + k0 + s * 8;
            gload_lds16(g, ((char*)&lsA[buf][0]) + b);
        }
    };

    int nk = K >> 6;
    stage(0, 0);
    for (int kt = 0; kt < nk; ++kt) {
        int cur = kt & 1;
        __syncthreads();  // buf[cur] staged; all waves' prior LDS reads done
        half8 bf[2][4];
#pragma unroll
        for (int ks = 0; ks < 2; ++ks)
#pragma unroll
            for (int fn = 0; fn < 4; ++fn) {
                size_t off = (size_t)(bcol + wn + fn * 16 + l16) * K + (kt << 6) + ks * 32 + lhi * 8;
                bf[ks][fn] = *(const half8*)(BT + off);
            }
        if (kt + 1 < nk) stage(cur ^ 1, (kt + 1) << 6);
#pragma unroll
        for (int ks = 0; ks < 2; ++ks)
#pragma unroll
            for (int fm = 0; fm < 4; ++fm) {
                int row = wm + fm * 16 + l16;
                int sidx = (ks * 4 + lhi) ^ (row & 7);
                half8 af = *(const half8*)(&lsA[cur][0] + row * 64 + sidx * 8);
#pragma unroll
                for (int fn = 0; fn < 4; ++fn)
                    acc[fm][fn] = __builtin_amdgcn_mfma_f32_16x16x32_f16(bf[ks][fn], af, acc[fm][fn], 0, 0, 0);
            }
    }

    // epilogue: C^T frags: m = ...+l16, n-block = ...+lhi*4 (4 consecutive n)
#pragma unroll
    for (int fm = 0; fm < 4; ++fm) {
        int m = brow + wm + fm * 16 + l16;
        if (m >= M) continue;
#pragma unroll
        for (int fn = 0; fn < 4; ++fn) {
            int nb = bcol + wn + fn * 16 + lhi * 4;
            if (F16OUT) {
                v4f bv = *(const v4f*)(bias + nb);
                v4f v = acc[fm][fn] + bv;
                if (RELU) {
#pragma unroll
                    for (int rr = 0; rr < 4; ++rr) v[rr] = fmaxf(v[rr], 0.f);
                }
                half4 hv = {(f16)v[0], (f16)v[1], (f16)v[2], (f16)v[3]};
                *(half4*)(Ch + (size_t)m * N + nb) = hv;
            } else {
#pragma unroll
                for (int rr = 0; rr < 4; ++rr) {
                    int nn = nb + rr;
                    if (nn < N) {
                        float v = acc[fm][fn][rr] + bias[nn];
                        if (RELU) v = fmaxf(v, 0.f);
                        Cf[(size_t)m * N + nn] = v;
                    }
                }
            }
        }
    }
}

// ------------------------------ log_softmax -------------------------------

__device__ inline float wred_max(float v) {
#pragma unroll
    for (int o = 32; o; o >>= 1) v = fmaxf(v, __shfl_xor(v, o));
    return v;
}
__device__ inline float wred_sum(float v) {
#pragma unroll
    for (int o = 32; o; o >>= 1) v += __shfl_xor(v, o);
    return v;
}

__global__ __launch_bounds__(256) void k_lsm(const float* __restrict__ in, float* __restrict__ out, int n) {
    int gw = (int)((blockIdx.x * blockDim.x + threadIdx.x) >> 6);
    int lane = threadIdx.x & 63;
    if (gw >= n) return;
    float v = (lane < 40) ? in[(size_t)gw * 40 + lane] : -INFINITY;
    float m = wred_max(v);
    float e = (lane < 40) ? __expf(v - m) : 0.f;
    float s = wred_sum(e);
    if (lane < 40) out[(size_t)gw * 40 + lane] = v - m - __logf(s);
}

// ------------------------------ host --------------------------------------

extern "C" void kernel_launch(void* const* d_in, const int* in_sizes, int n_in,
                              void* d_out, int out_size, void* d_ws, size_t ws_size,
                              hipStream_t stream) {
    const float* x   = (const float*)d_in[0];
    const int*   ei  = (const int*)d_in[1];
    const float* ea  = (const float*)d_in[2];
    const float* W1  = (const float*)d_in[3];  const float* b1  = (const float*)d_in[4];
    const float* W2  = (const float*)d_in[5];  const float* b2  = (const float*)d_in[6];
    const float* W3  = (const float*)d_in[7];  const float* b3  = (const float*)d_in[8];
    const float* fW1 = (const float*)d_in[9];  const float* fb1 = (const float*)d_in[10];
    const float* fW2 = (const float*)d_in[11]; const float* fb2 = (const float*)d_in[12];

    int n = in_sizes[0] / 64;
    int E = in_sizes[1] / 2;
    int Mp = ((n + 127) / 128) * 128;
    const int* src = ei;
    const int* dst = ei + E;
    float* out = (float*)d_out;

    char* p = (char*)d_ws;
    auto alloc = [&](size_t bytes) -> char* {
        char* r = p;
        p += (bytes + 255) & ~(size_t)255;
        return r;
    };
    int nb256 = (n + 255) / 256;
    float* deg      = (float*)alloc((size_t)n * 4);
    float* dinv     = (float*)alloc((size_t)n * 4);
    int*   cnt      = (int*)alloc((size_t)n * 4);
    int*   cursor   = (int*)alloc((size_t)n * 4);
    int*   rowptr   = (int*)alloc((size_t)(n + 1) * 4);
    int*   bsum     = (int*)alloc((size_t)nb256 * 4);
    int*   boff     = (int*)alloc((size_t)nb256 * 4);
    int*   csr_src  = (int*)alloc((size_t)E * 4);
    float* csr_norm = (float*)alloc((size_t)E * 4);
    f16* XH  = (f16*)alloc((size_t)n * 64 * 2);
    f16* W1T = (f16*)alloc((size_t)128 * 64 * 2);
    f16* W2T = (f16*)alloc((size_t)256 * 128 * 2);
    f16* W3T = (f16*)alloc((size_t)512 * 256 * 2);
    f16* F1T = (f16*)alloc((size_t)512 * 512 * 2);
    f16* F2T = (f16*)alloc((size_t)128 * 512 * 2);
    f16* AGG = (f16*)alloc((size_t)Mp * 256 * 2);
    f16* HA  = (f16*)alloc((size_t)Mp * 512 * 2);
    f16* HB  = (f16*)alloc((size_t)Mp * 512 * 2);
    float* logits = (float*)alloc((size_t)Mp * 40 * 4);

    const int tb = 256;
    int nBk = (n + tb - 1) / tb;
    int eB = (E + tb - 1) / tb;
    int waveB = (int)(((size_t)n * 64 + tb - 1) / tb);
    auto aggB = [&](int npw) {
        long waves = (n + npw - 1) / npw;
        return (int)((waves * 64 + tb - 1) / tb);
    };

    // graph prep
    k_init<<<nBk, tb, 0, stream>>>(deg, cnt, cursor, n);
    k_edge1<<<eB, tb, 0, stream>>>(src, dst, ea, deg, cnt, E);
    k_dinv<<<nBk, tb, 0, stream>>>(deg, dinv, n);
    k_scan1<<<nb256, tb, 0, stream>>>(cnt, bsum, n);
    k_scan2<<<1, tb, 0, stream>>>(bsum, boff, rowptr + n, nb256);
    k_scan3<<<nb256, tb, 0, stream>>>(cnt, boff, rowptr, n);
    k_fill<<<eB, tb, 0, stream>>>(src, dst, ea, dinv, rowptr, cursor, csr_src, csr_norm, E);

    // x -> f16
    k_xcast<<<(n * 64 / 4 + tb - 1) / tb, tb, 0, stream>>>(x, XH, n * 64 / 4);

    // fused weight prep
    {
        WPrepArgs a;
        a.W[0] = W1;  a.WT[0] = W1T; a.lgK[0] = 6; a.N[0] = 128;
        a.W[1] = W2;  a.WT[1] = W2T; a.lgK[1] = 7; a.N[1] = 256;
        a.W[2] = W3;  a.WT[2] = W3T; a.lgK[2] = 8; a.N[2] = 512;
        a.W[3] = fW1; a.WT[3] = F1T; a.lgK[3] = 9; a.N[3] = 512;
        a.W[4] = fW2; a.WT[4] = F2T; a.lgK[4] = 9; a.N[4] = 40;
        a.off[0] = 0;
        a.off[1] = a.off[0] + 128 * 64;
        a.off[2] = a.off[1] + 256 * 128;
        a.off[3] = a.off[2] + 512 * 256;
        a.off[4] = a.off[3] + 512 * 512;
        a.off[5] = a.off[4] + 128 * 512;
        k_wprep_all<<<(a.off[5] + tb - 1) / tb, tb, 0, stream>>>(a);
    }

    int mB = Mp / 128;
    auto mm = [&](const f16* a, const f16* bt, const float* bias, f16* ch, float* cf,
                  int N, int Np, int K, bool relu_f16) {
        int nB2 = Np / 128;
        int nwg = mB * nB2;
        if (relu_f16)
            k_mm<true, true><<<nwg, 256, 0, stream>>>(a, bt, bias, ch, cf, n, N, K, nB2, nwg);
        else
            k_mm<false, false><<<nwg, 256, 0, stream>>>(a, bt, bias, ch, cf, n, N, K, nB2, nwg);
    };

    // conv1: agg(xh)[.,64] -> @W1 relu -> HA[.,128]
    k_agg<64><<<aggB(8), tb, 0, stream>>>(XH, dinv, rowptr, csr_src, csr_norm, AGG, n);
    mm(AGG, W1T, b1, HA, nullptr, 128, 128, 64, true);
    // conv2: agg(HA)[.,128] -> @W2 relu -> HB[.,256]
    k_agg<128><<<aggB(4), tb, 0, stream>>>(HA, dinv, rowptr, csr_src, csr_norm, AGG, n);
    mm(AGG, W2T, b2, HB, nullptr, 256, 256, 128, true);
    // conv3: agg(HB)[.,256] -> @W3 relu -> HA[.,512]
    k_agg<256><<<aggB(2), tb, 0, stream>>>(HB, dinv, rowptr, csr_src, csr_norm, AGG, n);
    mm(AGG, W3T, b3, HA, nullptr, 512, 512, 256, true);
    // fc1: HA @ fW1 relu -> HB[.,512]
    mm(HA, F1T, fb1, HB, nullptr, 512, 512, 512, true);
    // fc2: HB @ fW2 -> logits f32 [.,40]
    mm(HB, F2T, fb2, nullptr, logits, 40, 128, 512, false);
    // log_softmax
    k_lsm<<<waveB, tb, 0, stream>>>(logits, out, n);
}

// Round 6
// 252.054 us; speedup vs baseline: 2.8431x; 1.1431x over previous
//
#include <hip/hip_runtime.h>
#include <cstdint>
#include <cstddef>

// ---------------------------------------------------------------------------
// GCN 3-conv + MLP head. FP16 single-product MFMA GEMMs (f32 accumulate),
// f16 activations, aggregate-before-linear (A(xW) == (Ax)W, Fin<Fout).
// GEMM: A AND B staged to LDS via global_load_lds (XOR-swizzled both sides),
// double-buffered, one barrier per k-step; operand-swapped MFMA -> C^T frags
// -> coalesced 8B stores. Templated wave grid (2x2 / 4x1 tiles).
// ---------------------------------------------------------------------------

typedef _Float16 f16;
typedef _Float16 half8 __attribute__((ext_vector_type(8)));
typedef _Float16 half4 __attribute__((ext_vector_type(4)));
typedef float v4f __attribute__((ext_vector_type(4)));

__device__ inline void gload_lds16(const void* g, void* l) {
    __builtin_amdgcn_global_load_lds(
        (const __attribute__((address_space(1))) unsigned int*)g,
        (__attribute__((address_space(3))) unsigned int*)l, 16, 0, 0);
}

// ------------------------------ graph prep --------------------------------

__global__ __launch_bounds__(256) void k_init(float* deg, int* cnt, int* cursor, int n) {
    int i = blockIdx.x * blockDim.x + threadIdx.x;
    if (i < n) { deg[i] = 1.0f; cnt[i] = 0; cursor[i] = 0; }
}

__global__ __launch_bounds__(256) void k_edge1(const int* __restrict__ src, const int* __restrict__ dst,
                                               const float* __restrict__ ew,
                                               float* deg, int* cnt, int E) {
    int e = blockIdx.x * blockDim.x + threadIdx.x;
    if (e < E) {
        int d = dst[e];
        atomicAdd(&deg[d], ew[e]);
        atomicAdd(&cnt[d], 1);
    }
}

// fused: dinv (Newton-refined rsqrt) + per-block cnt sums for the scan
__global__ __launch_bounds__(256) void k_dinv_scan1(const float* __restrict__ deg, const int* __restrict__ cnt,
                                                    float* __restrict__ dinv, int* __restrict__ bsum, int n) {
    int i = blockIdx.x * 256 + threadIdx.x;
    if (i < n) {
        float d = deg[i];
        float r = (d > 0.f) ? rsqrtf(d) : 0.f;
        r = r * (1.5f - 0.5f * d * r * r);
        dinv[i] = r;
    }
    int v = (i < n) ? cnt[i] : 0;
#pragma unroll
    for (int o = 32; o; o >>= 1) v += __shfl_xor(v, o);
    __shared__ int s[4];
    if ((threadIdx.x & 63) == 0) s[threadIdx.x >> 6] = v;
    __syncthreads();
    if (threadIdx.x == 0) bsum[blockIdx.x] = s[0] + s[1] + s[2] + s[3];
}

// 256-thread inclusive block scan (shfl wave scan + LDS wave offsets).
__device__ inline int block_scan_incl(int v) {
    __shared__ int ws[4];
    int lane = threadIdx.x & 63, w = threadIdx.x >> 6;
#pragma unroll
    for (int off = 1; off < 64; off <<= 1) {
        int t = __shfl_up(v, off);
        if (lane >= off) v += t;
    }
    if (lane == 63) ws[w] = v;
    __syncthreads();
    int add = 0;
#pragma unroll
    for (int i = 0; i < 4; ++i) add += (i < w) ? ws[i] : 0;
    __syncthreads();
    return v + add;
}

// exclusive scan of block sums (single block) + total -> rowptr[n]
__global__ __launch_bounds__(256) void k_scan2(const int* __restrict__ bsum, int* __restrict__ boff,
                                               int* __restrict__ rowptr_last, int nb) {
    __shared__ int carry;
    if (threadIdx.x == 0) carry = 0;
    __syncthreads();
    for (int base = 0; base < nb; base += 256) {
        int i = base + threadIdx.x;
        int v = (i < nb) ? bsum[i] : 0;
        int incl = block_scan_incl(v);
        int c = carry;
        if (i < nb) boff[i] = c + incl - v;
        __syncthreads();
        if (threadIdx.x == 255) carry = c + incl;
        __syncthreads();
    }
    if (threadIdx.x == 0) *rowptr_last = carry;
}

// local exclusive scan + block offset -> rowptr[0..n)
__global__ __launch_bounds__(256) void k_scan3(const int* __restrict__ cnt, const int* __restrict__ boff,
                                               int* __restrict__ rowptr, int n) {
    int i = blockIdx.x * 256 + threadIdx.x;
    int v = (i < n) ? cnt[i] : 0;
    int incl = block_scan_incl(v);
    if (i < n) rowptr[i] = boff[blockIdx.x] + incl - v;
}

__global__ __launch_bounds__(256) void k_fill(const int* __restrict__ src, const int* __restrict__ dst,
                                              const float* __restrict__ ew, const float* __restrict__ dinv,
                                              const int* __restrict__ rowptr, int* __restrict__ cursor,
                                              int* __restrict__ csr_src, float* __restrict__ csr_norm, int E) {
    int e = blockIdx.x * blockDim.x + threadIdx.x;
    if (e < E) {
        int d = dst[e], s = src[e];
        int p = atomicAdd(&cursor[d], 1);
        int idx = rowptr[d] + p;
        csr_src[idx] = s;
        csr_norm[idx] = dinv[s] * ew[e] * dinv[d];
    }
}

// fused cast: x f32->f16 (4/thread) + 5 weight transposes W[K,N]->WT[Np,K]
struct PrepArgs {
    const float* x; f16* xh; int xt4;
    const float* W[5]; f16* WT[5];
    int lgK[5]; int N[5]; int off[6];
};
__global__ __launch_bounds__(256) void k_prep_cast(PrepArgs a) {
    int i = blockIdx.x * 256 + threadIdx.x;
    if (i < a.xt4) {
        float4 v = *(const float4*)(a.x + (size_t)i * 4);
        half4 h = {(f16)v.x, (f16)v.y, (f16)v.z, (f16)v.w};
        *(half4*)(a.xh + (size_t)i * 4) = h;
        return;
    }
    int w = i - a.xt4;
#pragma unroll
    for (int s = 0; s < 5; ++s) {
        if (w >= a.off[s] && w < a.off[s + 1]) {
            int li = w - a.off[s];
            int K = 1 << a.lgK[s];
            int nr = li >> a.lgK[s], k = li & (K - 1);
            float v = (nr < a.N[s]) ? a.W[s][(size_t)k * a.N[s] + nr] : 0.f;
            a.WT[s][li] = (f16)v;
        }
    }
}

// ------------------------------ aggregation -------------------------------
// out[i,:] = dinv[i]^2*h[i,:] + sum_j norm_j*h[src_j,:]; f16 in/out, f32 acc.
// 8 f16 (16B) per lane; LPN lanes per node; NPW nodes per wave; 4-edge unroll.
template <int F>
__global__ __launch_bounds__(256) void k_agg(const f16* __restrict__ h,
                                             const float* __restrict__ dinv, const int* __restrict__ rowptr,
                                             const int* __restrict__ csr_src, const float* __restrict__ csr_norm,
                                             f16* __restrict__ o, int n) {
    constexpr int LPN = F / 8;
    constexpr int NPW = 64 / LPN;
    int wave = (int)((blockIdx.x * (unsigned)blockDim.x + threadIdx.x) >> 6);
    int lane = threadIdx.x & 63;
    int grp = lane / LPN, lin = lane % LPN;
    int node = wave * NPW + grp;
    if (node >= n) return;
    float di = dinv[node], w0 = di * di;
    float acc[8];
#pragma unroll
    for (int i = 0; i < 8; ++i) acc[i] = 0.f;

    auto gat = [&](int s, float w) {
        half8 x = *(const half8*)(h + (size_t)s * F + lin * 8);
#pragma unroll
        for (int i = 0; i < 8; ++i) acc[i] += w * (float)x[i];
    };

    gat(node, w0);
    int beg = rowptr[node], end = rowptr[node + 1];
    int j = beg;
    for (; j + 3 < end; j += 4) {  // 4 independent gathers in flight
        int s0 = csr_src[j], s1 = csr_src[j + 1], s2 = csr_src[j + 2], s3 = csr_src[j + 3];
        float u0 = csr_norm[j], u1 = csr_norm[j + 1], u2 = csr_norm[j + 2], u3 = csr_norm[j + 3];
        gat(s0, u0); gat(s1, u1); gat(s2, u2); gat(s3, u3);
    }
    for (; j < end; ++j) gat(csr_src[j], csr_norm[j]);

    half8 v;
#pragma unroll
    for (int i = 0; i < 8; ++i) v[i] = (f16)acc[i];
    *(half8*)(o + (size_t)node * F + (size_t)lin * 8) = v;
}

// ------------------------------ MFMA GEMM ---------------------------------
// C[M,N] = act(A[M,K] @ B[K,N] + bias). A f16 row-major [*,K], BT f16 [Np,K].
// Tile (WR*64) x (WC*64), BK=64, 4 waves (WRxWC grid). Both A and B tiles
// staged via global_load_lds (XOR-swizzle: inverse-swz source, swz ds_read),
// double-buffered; stage(next) issued before current ds_reads so the DMA
// flies under the MFMA block. One barrier per k-step (min-2-phase).
template <int WR, int WC, bool RELU, bool F16OUT>
__global__ __launch_bounds__(256) void k_mm(const f16* __restrict__ A, const f16* __restrict__ BT,
                                            const float* __restrict__ bias,
                                            f16* __restrict__ Ch, float* __restrict__ Cf,
                                            int M, int N, int K, int nB, int nwg) {
    constexpr int TM = WR * 64, TN = WC * 64;
    __shared__ f16 lsA[2][TM * 64];
    __shared__ f16 lsB[2][TN * 64];

    // bijective XCD-aware block swizzle (m204)
    int wg = blockIdx.x;
    int q = nwg >> 3, r = nwg & 7;
    int xcd = wg & 7, lin = wg >> 3;
    int wgs = (xcd < r) ? (xcd * (q + 1) + lin) : (r * (q + 1) + (xcd - r) * q + lin);
    int bm = wgs / nB, bn = wgs % nB;

    int tid = threadIdx.x;
    int lane = tid & 63, wid = tid >> 6;
    int l16 = lane & 15, lhi = lane >> 4;
    int wm = (wid / WC) * 64, wn = (wid % WC) * 64;
    int brow = bm * TM, bcol = bn * TN;

    v4f acc[4][4] = {};

    auto stageA = [&](int buf, int k0) {
#pragma unroll
        for (int it = 0; it < TM / 32; ++it) {
            int b = it * 4096 + tid * 16;
            int row = b >> 7;
            int s = ((b >> 4) & 7) ^ (row & 7);
            gload_lds16(A + (size_t)(brow + row) * K + k0 + s * 8, ((char*)&lsA[buf][0]) + b);
        }
    };
    auto stageB = [&](int buf, int k0) {
#pragma unroll
        for (int it = 0; it < TN / 32; ++it) {
            int b = it * 4096 + tid * 16;
            int row = b >> 7;
            int s = ((b >> 4) & 7) ^ (row & 7);
            gload_lds16(BT + (size_t)(bcol + row) * K + k0 + s * 8, ((char*)&lsB[buf][0]) + b);
        }
    };

    int nk = K >> 6;
    stageA(0, 0);
    stageB(0, 0);
    for (int kt = 0; kt < nk; ++kt) {
        int cur = kt & 1;
        __syncthreads();  // buf[cur] DMA drained; all waves' prior LDS reads done
        if (kt + 1 < nk) {  // prefetch next tile under this step's compute
            stageA(cur ^ 1, (kt + 1) << 6);
            stageB(cur ^ 1, (kt + 1) << 6);
        }
        half8 bf[2][4];
#pragma unroll
        for (int ks = 0; ks < 2; ++ks)
#pragma unroll
            for (int fn = 0; fn < 4; ++fn) {
                int row = wn + fn * 16 + l16;
                int sidx = (ks * 4 + lhi) ^ (row & 7);
                bf[ks][fn] = *(const half8*)(&lsB[cur][0] + row * 64 + sidx * 8);
            }
#pragma unroll
        for (int ks = 0; ks < 2; ++ks)
#pragma unroll
            for (int fm = 0; fm < 4; ++fm) {
                int row = wm + fm * 16 + l16;
                int sidx = (ks * 4 + lhi) ^ (row & 7);
                half8 af = *(const half8*)(&lsA[cur][0] + row * 64 + sidx * 8);
#pragma unroll
                for (int fn = 0; fn < 4; ++fn)
                    acc[fm][fn] = __builtin_amdgcn_mfma_f32_16x16x32_f16(bf[ks][fn], af, acc[fm][fn], 0, 0, 0);
            }
    }

    // epilogue: C^T frags: m = ...+l16, n-block = ...+lhi*4 (4 consecutive n)
#pragma unroll
    for (int fm = 0; fm < 4; ++fm) {
        int m = brow + wm + fm * 16 + l16;
        if (m >= M) continue;
#pragma unroll
        for (int fn = 0; fn < 4; ++fn) {
            int nb = bcol + wn + fn * 16 + lhi * 4;
            if (F16OUT) {
                v4f bv = *(const v4f*)(bias + nb);
                v4f v = acc[fm][fn] + bv;
                if (RELU) {
#pragma unroll
                    for (int rr = 0; rr < 4; ++rr) v[rr] = fmaxf(v[rr], 0.f);
                }
                half4 hv = {(f16)v[0], (f16)v[1], (f16)v[2], (f16)v[3]};
                *(half4*)(Ch + (size_t)m * N + nb) = hv;
            } else {
#pragma unroll
                for (int rr = 0; rr < 4; ++rr) {
                    int nn = nb + rr;
                    if (nn < N) {
                        float v = acc[fm][fn][rr] + bias[nn];
                        if (RELU) v = fmaxf(v, 0.f);
                        Cf[(size_t)m * N + nn] = v;
                    }
                }
            }
        }
    }
}

// ------------------------------ log_softmax -------------------------------

__device__ inline float wred_max(float v) {
#pragma unroll
    for (int o = 32; o; o >>= 1) v = fmaxf(v, __shfl_xor(v, o));
    return v;
}
__device__ inline float wred_sum(float v) {
#pragma unroll
    for (int o = 32; o; o >>= 1) v += __shfl_xor(v, o);
    return v;
}

__global__ __launch_bounds__(256) void k_lsm(const float* __restrict__ in, float* __restrict__ out, int n) {
    int gw = (int)((blockIdx.x * blockDim.x + threadIdx.x) >> 6);
    int lane = threadIdx.x & 63;
    if (gw >= n) return;
    float v = (lane < 40) ? in[(size_t)gw * 40 + lane] : -INFINITY;
    float m = wred_max(v);
    float e = (lane < 40) ? __expf(v - m) : 0.f;
    float s = wred_sum(e);
    if (lane < 40) out[(size_t)gw * 40 + lane] = v - m - __logf(s);
}

// ------------------------------ host --------------------------------------

extern "C" void kernel_launch(void* const* d_in, const int* in_sizes, int n_in,
                              void* d_out, int out_size, void* d_ws, size_t ws_size,
                              hipStream_t stream) {
    const float* x   = (const float*)d_in[0];
    const int*   ei  = (const int*)d_in[1];
    const float* ea  = (const float*)d_in[2];
    const float* W1  = (const float*)d_in[3];  const float* b1  = (const float*)d_in[4];
    const float* W2  = (const float*)d_in[5];  const float* b2  = (const float*)d_in[6];
    const float* W3  = (const float*)d_in[7];  const float* b3  = (const float*)d_in[8];
    const float* fW1 = (const float*)d_in[9];  const float* fb1 = (const float*)d_in[10];
    const float* fW2 = (const float*)d_in[11]; const float* fb2 = (const float*)d_in[12];

    int n = in_sizes[0] / 64;
    int E = in_sizes[1] / 2;
    int Mpad = ((n + 255) / 256) * 256;  // covers both 128- and 256-row tiles
    const int* src = ei;
    const int* dst = ei + E;
    float* out = (float*)d_out;

    char* p = (char*)d_ws;
    auto alloc = [&](size_t bytes) -> char* {
        char* r = p;
        p += (bytes + 255) & ~(size_t)255;
        return r;
    };
    int nb256 = (n + 255) / 256;
    float* deg      = (float*)alloc((size_t)n * 4);
    float* dinv     = (float*)alloc((size_t)n * 4);
    int*   cnt      = (int*)alloc((size_t)n * 4);
    int*   cursor   = (int*)alloc((size_t)n * 4);
    int*   rowptr   = (int*)alloc((size_t)(n + 1) * 4);
    int*   bsum     = (int*)alloc((size_t)nb256 * 4);
    int*   boff     = (int*)alloc((size_t)nb256 * 4);
    int*   csr_src  = (int*)alloc((size_t)E * 4);
    float* csr_norm = (float*)alloc((size_t)E * 4);
    f16* XH  = (f16*)alloc((size_t)Mpad * 64 * 2);
    f16* W1T = (f16*)alloc((size_t)128 * 64 * 2);
    f16* W2T = (f16*)alloc((size_t)256 * 128 * 2);
    f16* W3T = (f16*)alloc((size_t)512 * 256 * 2);
    f16* F1T = (f16*)alloc((size_t)512 * 512 * 2);
    f16* F2T = (f16*)alloc((size_t)128 * 512 * 2);
    f16* AGG = (f16*)alloc((size_t)Mpad * 256 * 2);
    f16* HA  = (f16*)alloc((size_t)Mpad * 512 * 2);
    f16* HB  = (f16*)alloc((size_t)Mpad * 512 * 2);
    float* logits = (float*)alloc((size_t)Mpad * 40 * 4);

    const int tb = 256;
    int nBk = (n + tb - 1) / tb;
    int eB = (E + tb - 1) / tb;
    int waveB = (int)(((size_t)n * 64 + tb - 1) / tb);
    auto aggB = [&](int npw) {
        long waves = (n + npw - 1) / npw;
        return (int)((waves * 64 + tb - 1) / tb);
    };

    // graph prep
    k_init<<<nBk, tb, 0, stream>>>(deg, cnt, cursor, n);
    k_edge1<<<eB, tb, 0, stream>>>(src, dst, ea, deg, cnt, E);
    k_dinv_scan1<<<nb256, tb, 0, stream>>>(deg, cnt, dinv, bsum, n);
    k_scan2<<<1, tb, 0, stream>>>(bsum, boff, rowptr + n, nb256);
    k_scan3<<<nb256, tb, 0, stream>>>(cnt, boff, rowptr, n);
    k_fill<<<eB, tb, 0, stream>>>(src, dst, ea, dinv, rowptr, cursor, csr_src, csr_norm, E);

    // fused x-cast + weight transposes
    {
        PrepArgs a;
        a.x = x; a.xh = XH; a.xt4 = n * 16;
        a.W[0] = W1;  a.WT[0] = W1T; a.lgK[0] = 6; a.N[0] = 128;
        a.W[1] = W2;  a.WT[1] = W2T; a.lgK[1] = 7; a.N[1] = 256;
        a.W[2] = W3;  a.WT[2] = W3T; a.lgK[2] = 8; a.N[2] = 512;
        a.W[3] = fW1; a.WT[3] = F1T; a.lgK[3] = 9; a.N[3] = 512;
        a.W[4] = fW2; a.WT[4] = F2T; a.lgK[4] = 9; a.N[4] = 40;
        a.off[0] = 0;
        a.off[1] = a.off[0] + 128 * 64;
        a.off[2] = a.off[1] + 256 * 128;
        a.off[3] = a.off[2] + 512 * 256;
        a.off[4] = a.off[3] + 512 * 512;
        a.off[5] = a.off[4] + 128 * 512;
        int tot = a.xt4 + a.off[5];
        k_prep_cast<<<(tot + tb - 1) / tb, tb, 0, stream>>>(a);
    }

    int mB22 = Mpad / 128;
    auto mm22 = [&](const f16* a, const f16* bt, const float* bias, f16* ch, int N, int K) {
        int nB2 = N / 128;
        int nwg = mB22 * nB2;
        k_mm<2, 2, true, true><<<nwg, 256, 0, stream>>>(a, bt, bias, ch, nullptr, n, N, K, nB2, nwg);
    };

    // conv1: agg(xh)[.,64] -> @W1 relu -> HA[.,128]
    k_agg<64><<<aggB(8), tb, 0, stream>>>(XH, dinv, rowptr, csr_src, csr_norm, AGG, n);
    mm22(AGG, W1T, b1, HA, 128, 64);
    // conv2: agg(HA)[.,128] -> @W2 relu -> HB[.,256]
    k_agg<128><<<aggB(4), tb, 0, stream>>>(HA, dinv, rowptr, csr_src, csr_norm, AGG, n);
    mm22(AGG, W2T, b2, HB, 256, 128);
    // conv3: agg(HB)[.,256] -> @W3 relu -> HA[.,512]
    k_agg<256><<<aggB(2), tb, 0, stream>>>(HB, dinv, rowptr, csr_src, csr_norm, AGG, n);
    mm22(AGG, W3T, b3, HA, 512, 256);
    // fc1: HA @ fW1 relu -> HB[.,512]
    mm22(HA, F1T, fb1, HB, 512, 512);
    // fc2: HB @ fW2 -> logits f32 [.,40]  (256x64 tiles: no dead columns)
    {
        int nwg = Mpad / 256;
        k_mm<4, 1, false, false><<<nwg, 256, 0, stream>>>(HB, F2T, fb2, nullptr, logits, n, 40, 512, 1, nwg);
    }
    // log_softmax
    k_lsm<<<waveB, tb, 0, stream>>>(logits, out, n);
}

// Round 7
// 219.357 us; speedup vs baseline: 3.2669x; 1.1491x over previous
//
#include <hip/hip_runtime.h>
#include <cstdint>
#include <cstddef>

// ---------------------------------------------------------------------------
// GCN 3-conv + MLP head. FP16 single-product MFMA GEMMs (f32 accumulate),
// f16 activations, aggregate-before-linear (A(xW) == (Ax)W, Fin<Fout).
// Degree histogram: ONE packed u64 atomic per edge (cnt in low 24 bits,
// fixed-point weighted degree in high 40); atomic's return value gives each
// edge its CSR slot -> k_fill is atomic-free.
// ---------------------------------------------------------------------------

typedef _Float16 f16;
typedef _Float16 half8 __attribute__((ext_vector_type(8)));
typedef _Float16 half4 __attribute__((ext_vector_type(4)));
typedef float v4f __attribute__((ext_vector_type(4)));
typedef unsigned long long u64;

__device__ inline void gload_lds16(const void* g, void* l) {
    __builtin_amdgcn_global_load_lds(
        (const __attribute__((address_space(1))) unsigned int*)g,
        (__attribute__((address_space(3))) unsigned int*)l, 16, 0, 0);
}

// ------------------------------ graph prep --------------------------------

__global__ __launch_bounds__(256) void k_init(u64* packed, int n) {
    int i = blockIdx.x * blockDim.x + threadIdx.x;
    if (i < n) packed[i] = 0ULL;
}

// one packed atomic per edge; old value -> CSR slot within dst bucket
__global__ __launch_bounds__(256) void k_edge1(const int* __restrict__ dst, const float* __restrict__ ew,
                                               u64* __restrict__ packed, int* __restrict__ eslot, int E) {
    int t = blockIdx.x * blockDim.x + threadIdx.x;
    int e0 = t * 4;
    if (e0 + 3 < E) {
        int4 d4 = *(const int4*)(dst + e0);
        float4 w4 = *(const float4*)(ew + e0);
        u64 a0 = ((u64)__float2uint_rn(w4.x * 1048576.f) << 24) | 1ULL;
        u64 a1 = ((u64)__float2uint_rn(w4.y * 1048576.f) << 24) | 1ULL;
        u64 a2 = ((u64)__float2uint_rn(w4.z * 1048576.f) << 24) | 1ULL;
        u64 a3 = ((u64)__float2uint_rn(w4.w * 1048576.f) << 24) | 1ULL;
        u64 o0 = atomicAdd(&packed[d4.x], a0);
        u64 o1 = atomicAdd(&packed[d4.y], a1);
        u64 o2 = atomicAdd(&packed[d4.z], a2);
        u64 o3 = atomicAdd(&packed[d4.w], a3);
        int4 s;
        s.x = (int)(o0 & 0xFFFFFF); s.y = (int)(o1 & 0xFFFFFF);
        s.z = (int)(o2 & 0xFFFFFF); s.w = (int)(o3 & 0xFFFFFF);
        *(int4*)(eslot + e0) = s;
    } else {
        for (int e = e0; e < E; ++e) {
            u64 a = ((u64)__float2uint_rn(ew[e] * 1048576.f) << 24) | 1ULL;
            u64 o = atomicAdd(&packed[dst[e]], a);
            eslot[e] = (int)(o & 0xFFFFFF);
        }
    }
}

// fused: dinv (Newton-refined rsqrt of unpacked degree) + per-block cnt sums
__global__ __launch_bounds__(256) void k_dinv_scan1(const u64* __restrict__ packed,
                                                    float* __restrict__ dinv, int* __restrict__ cnt,
                                                    int* __restrict__ bsum, int n) {
    int i = blockIdx.x * 256 + threadIdx.x;
    int c = 0;
    if (i < n) {
        u64 pk = packed[i];
        c = (int)(pk & 0xFFFFFF);
        float d = 1.0f + (float)(pk >> 24) * (1.0f / 1048576.f);  // self-loop + sum(ew)
        float r = rsqrtf(d);
        r = r * (1.5f - 0.5f * d * r * r);
        dinv[i] = r;
        cnt[i] = c;
    }
    int v = c;
#pragma unroll
    for (int o = 32; o; o >>= 1) v += __shfl_xor(v, o);
    __shared__ int s[4];
    if ((threadIdx.x & 63) == 0) s[threadIdx.x >> 6] = v;
    __syncthreads();
    if (threadIdx.x == 0) bsum[blockIdx.x] = s[0] + s[1] + s[2] + s[3];
}

// 256-thread inclusive block scan (shfl wave scan + LDS wave offsets).
__device__ inline int block_scan_incl(int v) {
    __shared__ int ws[4];
    int lane = threadIdx.x & 63, w = threadIdx.x >> 6;
#pragma unroll
    for (int off = 1; off < 64; off <<= 1) {
        int t = __shfl_up(v, off);
        if (lane >= off) v += t;
    }
    if (lane == 63) ws[w] = v;
    __syncthreads();
    int add = 0;
#pragma unroll
    for (int i = 0; i < 4; ++i) add += (i < w) ? ws[i] : 0;
    __syncthreads();
    return v + add;
}

// exclusive scan of block sums (single block)
__global__ __launch_bounds__(256) void k_scan2(const int* __restrict__ bsum, int* __restrict__ boff, int nb) {
    __shared__ int carry;
    if (threadIdx.x == 0) carry = 0;
    __syncthreads();
    for (int base = 0; base < nb; base += 256) {
        int i = base + threadIdx.x;
        int v = (i < nb) ? bsum[i] : 0;
        int incl = block_scan_incl(v);
        int c = carry;
        if (i < nb) boff[i] = c + incl - v;
        __syncthreads();
        if (threadIdx.x == 255) carry = c + incl;
        __syncthreads();
    }
}

// local exclusive scan + block offset -> rowptr[0..n)
__global__ __launch_bounds__(256) void k_scan3(const int* __restrict__ cnt, const int* __restrict__ boff,
                                               int* __restrict__ rowptr, int n) {
    int i = blockIdx.x * 256 + threadIdx.x;
    int v = (i < n) ? cnt[i] : 0;
    int incl = block_scan_incl(v);
    if (i < n) rowptr[i] = boff[blockIdx.x] + incl - v;
    if (i == n - 1) rowptr[n] = boff[blockIdx.x] + incl;  // total
}

// atomic-free CSR fill using precomputed slots
__global__ __launch_bounds__(256) void k_fill(const int* __restrict__ src, const int* __restrict__ dst,
                                              const float* __restrict__ ew, const int* __restrict__ eslot,
                                              const float* __restrict__ dinv, const int* __restrict__ rowptr,
                                              int* __restrict__ csr_src, float* __restrict__ csr_norm, int E) {
    int e = blockIdx.x * blockDim.x + threadIdx.x;
    if (e < E) {
        int d = dst[e], s = src[e];
        int idx = rowptr[d] + eslot[e];
        csr_src[idx] = s;
        csr_norm[idx] = dinv[s] * ew[e] * dinv[d];
    }
}

// fused cast: x f32->f16 (4/thread) + 5 weight transposes W[K,N]->WT[Np,K]
struct PrepArgs {
    const float* x; f16* xh; int xt4;
    const float* W[5]; f16* WT[5];
    int lgK[5]; int N[5]; int off[6];
};
__global__ __launch_bounds__(256) void k_prep_cast(PrepArgs a) {
    int i = blockIdx.x * 256 + threadIdx.x;
    if (i < a.xt4) {
        float4 v = *(const float4*)(a.x + (size_t)i * 4);
        half4 h = {(f16)v.x, (f16)v.y, (f16)v.z, (f16)v.w};
        *(half4*)(a.xh + (size_t)i * 4) = h;
        return;
    }
    int w = i - a.xt4;
#pragma unroll
    for (int s = 0; s < 5; ++s) {
        if (w >= a.off[s] && w < a.off[s + 1]) {
            int li = w - a.off[s];
            int K = 1 << a.lgK[s];
            int nr = li >> a.lgK[s], k = li & (K - 1);
            float v = (nr < a.N[s]) ? a.W[s][(size_t)k * a.N[s] + nr] : 0.f;
            a.WT[s][li] = (f16)v;
        }
    }
}

// ------------------------------ aggregation -------------------------------
// out[i,:] = dinv[i]^2*h[i,:] + sum_j norm_j*h[src_j,:]; f16 in/out, f32 acc.
template <int F>
__global__ __launch_bounds__(256) void k_agg(const f16* __restrict__ h,
                                             const float* __restrict__ dinv, const int* __restrict__ rowptr,
                                             const int* __restrict__ csr_src, const float* __restrict__ csr_norm,
                                             f16* __restrict__ o, int n) {
    constexpr int LPN = F / 8;
    constexpr int NPW = 64 / LPN;
    int wave = (int)((blockIdx.x * (unsigned)blockDim.x + threadIdx.x) >> 6);
    int lane = threadIdx.x & 63;
    int grp = lane / LPN, lin = lane % LPN;
    int node = wave * NPW + grp;
    if (node >= n) return;
    float di = dinv[node], w0 = di * di;
    float acc[8];
#pragma unroll
    for (int i = 0; i < 8; ++i) acc[i] = 0.f;

    auto gat = [&](int s, float w) {
        half8 x = *(const half8*)(h + (size_t)s * F + lin * 8);
#pragma unroll
        for (int i = 0; i < 8; ++i) acc[i] += w * (float)x[i];
    };

    gat(node, w0);
    int beg = rowptr[node], end = rowptr[node + 1];
    int j = beg;
    for (; j + 3 < end; j += 4) {  // 4 independent gathers in flight
        int s0 = csr_src[j], s1 = csr_src[j + 1], s2 = csr_src[j + 2], s3 = csr_src[j + 3];
        float u0 = csr_norm[j], u1 = csr_norm[j + 1], u2 = csr_norm[j + 2], u3 = csr_norm[j + 3];
        gat(s0, u0); gat(s1, u1); gat(s2, u2); gat(s3, u3);
    }
    for (; j < end; ++j) gat(csr_src[j], csr_norm[j]);

    half8 v;
#pragma unroll
    for (int i = 0; i < 8; ++i) v[i] = (f16)acc[i];
    *(half8*)(o + (size_t)node * F + (size_t)lin * 8) = v;
}

// ------------------------------ MFMA GEMM ---------------------------------
// C[M,N] = act(A[M,K] @ B[K,N] + bias). A f16 row-major [*,K], BT f16 [Np,K].
// Tile (WR*64) x (WC*64), BK=64, 4 waves. A and B staged via global_load_lds
// (XOR-swizzle: inverse-swz source, swz ds_read), double-buffered; stage(next)
// issued before current ds_reads. Operand-swapped MFMA -> C^T frags -> 8B stores.
template <int WR, int WC, bool RELU, bool F16OUT>
__global__ __launch_bounds__(256) void k_mm(const f16* __restrict__ A, const f16* __restrict__ BT,
                                            const float* __restrict__ bias,
                                            f16* __restrict__ Ch, float* __restrict__ Cf,
                                            int M, int N, int K, int nB, int nwg) {
    constexpr int TM = WR * 64, TN = WC * 64;
    __shared__ f16 lsA[2][TM * 64];
    __shared__ f16 lsB[2][TN * 64];

    // bijective XCD-aware block swizzle (m204)
    int wg = blockIdx.x;
    int q = nwg >> 3, r = nwg & 7;
    int xcd = wg & 7, lin = wg >> 3;
    int wgs = (xcd < r) ? (xcd * (q + 1) + lin) : (r * (q + 1) + (xcd - r) * q + lin);
    int bm = wgs / nB, bn = wgs % nB;

    int tid = threadIdx.x;
    int lane = tid & 63, wid = tid >> 6;
    int l16 = lane & 15, lhi = lane >> 4;
    int wm = (wid / WC) * 64, wn = (wid % WC) * 64;
    int brow = bm * TM, bcol = bn * TN;

    v4f acc[4][4] = {};

    auto stageA = [&](int buf, int k0) {
#pragma unroll
        for (int it = 0; it < TM / 32; ++it) {
            int b = it * 4096 + tid * 16;
            int row = b >> 7;
            int s = ((b >> 4) & 7) ^ (row & 7);
            gload_lds16(A + (size_t)(brow + row) * K + k0 + s * 8, ((char*)&lsA[buf][0]) + b);
        }
    };
    auto stageB = [&](int buf, int k0) {
#pragma unroll
        for (int it = 0; it < TN / 32; ++it) {
            int b = it * 4096 + tid * 16;
            int row = b >> 7;
            int s = ((b >> 4) & 7) ^ (row & 7);
            gload_lds16(BT + (size_t)(bcol + row) * K + k0 + s * 8, ((char*)&lsB[buf][0]) + b);
        }
    };

    int nk = K >> 6;
    stageA(0, 0);
    stageB(0, 0);
    for (int kt = 0; kt < nk; ++kt) {
        int cur = kt & 1;
        __syncthreads();  // buf[cur] DMA drained; all waves' prior LDS reads done
        if (kt + 1 < nk) {  // prefetch next tile under this step's compute
            stageA(cur ^ 1, (kt + 1) << 6);
            stageB(cur ^ 1, (kt + 1) << 6);
        }
        half8 bf[2][4];
#pragma unroll
        for (int ks = 0; ks < 2; ++ks)
#pragma unroll
            for (int fn = 0; fn < 4; ++fn) {
                int row = wn + fn * 16 + l16;
                int sidx = (ks * 4 + lhi) ^ (row & 7);
                bf[ks][fn] = *(const half8*)(&lsB[cur][0] + row * 64 + sidx * 8);
            }
#pragma unroll
        for (int ks = 0; ks < 2; ++ks)
#pragma unroll
            for (int fm = 0; fm < 4; ++fm) {
                int row = wm + fm * 16 + l16;
                int sidx = (ks * 4 + lhi) ^ (row & 7);
                half8 af = *(const half8*)(&lsA[cur][0] + row * 64 + sidx * 8);
#pragma unroll
                for (int fn = 0; fn < 4; ++fn)
                    acc[fm][fn] = __builtin_amdgcn_mfma_f32_16x16x32_f16(bf[ks][fn], af, acc[fm][fn], 0, 0, 0);
            }
    }

    // epilogue: C^T frags: m = ...+l16, n-block = ...+lhi*4 (4 consecutive n)
#pragma unroll
    for (int fm = 0; fm < 4; ++fm) {
        int m = brow + wm + fm * 16 + l16;
        if (m >= M) continue;
#pragma unroll
        for (int fn = 0; fn < 4; ++fn) {
            int nb = bcol + wn + fn * 16 + lhi * 4;
            if (F16OUT) {
                v4f bv = *(const v4f*)(bias + nb);
                v4f v = acc[fm][fn] + bv;
                if (RELU) {
#pragma unroll
                    for (int rr = 0; rr < 4; ++rr) v[rr] = fmaxf(v[rr], 0.f);
                }
                half4 hv = {(f16)v[0], (f16)v[1], (f16)v[2], (f16)v[3]};
                *(half4*)(Ch + (size_t)m * N + nb) = hv;
            } else {
#pragma unroll
                for (int rr = 0; rr < 4; ++rr) {
                    int nn = nb + rr;
                    if (nn < N) {
                        float v = acc[fm][fn][rr] + bias[nn];
                        if (RELU) v = fmaxf(v, 0.f);
                        Cf[(size_t)m * N + nn] = v;
                    }
                }
            }
        }
    }
}

// ------------------------------ log_softmax -------------------------------

__device__ inline float wred_max(float v) {
#pragma unroll
    for (int o = 32; o; o >>= 1) v = fmaxf(v, __shfl_xor(v, o));
    return v;
}
__device__ inline float wred_sum(float v) {
#pragma unroll
    for (int o = 32; o; o >>= 1) v += __shfl_xor(v, o);
    return v;
}

__global__ __launch_bounds__(256) void k_lsm(const float* __restrict__ in, float* __restrict__ out, int n) {
    int gw = (int)((blockIdx.x * blockDim.x + threadIdx.x) >> 6);
    int lane = threadIdx.x & 63;
    if (gw >= n) return;
    float v = (lane < 40) ? in[(size_t)gw * 40 + lane] : -INFINITY;
    float m = wred_max(v);
    float e = (lane < 40) ? __expf(v - m) : 0.f;
    float s = wred_sum(e);
    if (lane < 40) out[(size_t)gw * 40 + lane] = v - m - __logf(s);
}

// ------------------------------ host --------------------------------------

extern "C" void kernel_launch(void* const* d_in, const int* in_sizes, int n_in,
                              void* d_out, int out_size, void* d_ws, size_t ws_size,
                              hipStream_t stream) {
    const float* x   = (const float*)d_in[0];
    const int*   ei  = (const int*)d_in[1];
    const float* ea  = (const float*)d_in[2];
    const float* W1  = (const float*)d_in[3];  const float* b1  = (const float*)d_in[4];
    const float* W2  = (const float*)d_in[5];  const float* b2  = (const float*)d_in[6];
    const float* W3  = (const float*)d_in[7];  const float* b3  = (const float*)d_in[8];
    const float* fW1 = (const float*)d_in[9];  const float* fb1 = (const float*)d_in[10];
    const float* fW2 = (const float*)d_in[11]; const float* fb2 = (const float*)d_in[12];

    int n = in_sizes[0] / 64;
    int E = in_sizes[1] / 2;
    int Mpad = ((n + 255) / 256) * 256;
    const int* src = ei;
    const int* dst = ei + E;
    float* out = (float*)d_out;

    char* p = (char*)d_ws;
    auto alloc = [&](size_t bytes) -> char* {
        char* r = p;
        p += (bytes + 255) & ~(size_t)255;
        return r;
    };
    int nb256 = (n + 255) / 256;
    u64*   packed   = (u64*)alloc((size_t)n * 8);
    float* dinv     = (float*)alloc((size_t)n * 4);
    int*   cnt      = (int*)alloc((size_t)n * 4);
    int*   rowptr   = (int*)alloc((size_t)(n + 1) * 4);
    int*   bsum     = (int*)alloc((size_t)nb256 * 4);
    int*   boff     = (int*)alloc((size_t)nb256 * 4);
    int*   eslot    = (int*)alloc((size_t)E * 4);
    int*   csr_src  = (int*)alloc((size_t)E * 4);
    float* csr_norm = (float*)alloc((size_t)E * 4);
    f16* XH  = (f16*)alloc((size_t)Mpad * 64 * 2);
    f16* W1T = (f16*)alloc((size_t)128 * 64 * 2);
    f16* W2T = (f16*)alloc((size_t)256 * 128 * 2);
    f16* W3T = (f16*)alloc((size_t)512 * 256 * 2);
    f16* F1T = (f16*)alloc((size_t)512 * 512 * 2);
    f16* F2T = (f16*)alloc((size_t)128 * 512 * 2);
    f16* AGG = (f16*)alloc((size_t)Mpad * 256 * 2);
    f16* HA  = (f16*)alloc((size_t)Mpad * 512 * 2);
    f16* HB  = (f16*)alloc((size_t)Mpad * 512 * 2);
    float* logits = (float*)alloc((size_t)Mpad * 40 * 4);

    const int tb = 256;
    int nBk = (n + tb - 1) / tb;
    int eB = (E + tb - 1) / tb;
    int e4B = (E / 4 + tb - 1) / tb + 1;
    int waveB = (int)(((size_t)n * 64 + tb - 1) / tb);
    auto aggB = [&](int npw) {
        long waves = (n + npw - 1) / npw;
        return (int)((waves * 64 + tb - 1) / tb);
    };

    // graph prep
    k_init<<<nBk, tb, 0, stream>>>(packed, n);
    k_edge1<<<e4B, tb, 0, stream>>>(dst, ea, packed, eslot, E);
    k_dinv_scan1<<<nb256, tb, 0, stream>>>(packed, dinv, cnt, bsum, n);
    k_scan2<<<1, tb, 0, stream>>>(bsum, boff, nb256);
    k_scan3<<<nb256, tb, 0, stream>>>(cnt, boff, rowptr, n);
    k_fill<<<eB, tb, 0, stream>>>(src, dst, ea, eslot, dinv, rowptr, csr_src, csr_norm, E);

    // fused x-cast + weight transposes
    {
        PrepArgs a;
        a.x = x; a.xh = XH; a.xt4 = n * 16;
        a.W[0] = W1;  a.WT[0] = W1T; a.lgK[0] = 6; a.N[0] = 128;
        a.W[1] = W2;  a.WT[1] = W2T; a.lgK[1] = 7; a.N[1] = 256;
        a.W[2] = W3;  a.WT[2] = W3T; a.lgK[2] = 8; a.N[2] = 512;
        a.W[3] = fW1; a.WT[3] = F1T; a.lgK[3] = 9; a.N[3] = 512;
        a.W[4] = fW2; a.WT[4] = F2T; a.lgK[4] = 9; a.N[4] = 40;
        a.off[0] = 0;
        a.off[1] = a.off[0] + 128 * 64;
        a.off[2] = a.off[1] + 256 * 128;
        a.off[3] = a.off[2] + 512 * 256;
        a.off[4] = a.off[3] + 512 * 512;
        a.off[5] = a.off[4] + 128 * 512;
        int tot = a.xt4 + a.off[5];
        k_prep_cast<<<(tot + tb - 1) / tb, tb, 0, stream>>>(a);
    }

    int mB22 = Mpad / 128;
    auto mm22 = [&](const f16* a, const f16* bt, const float* bias, f16* ch, int N, int K) {
        int nB2 = N / 128;
        int nwg = mB22 * nB2;
        k_mm<2, 2, true, true><<<nwg, 256, 0, stream>>>(a, bt, bias, ch, nullptr, n, N, K, nB2, nwg);
    };

    // conv1: agg(xh)[.,64] -> @W1 relu -> HA[.,128]
    k_agg<64><<<aggB(8), tb, 0, stream>>>(XH, dinv, rowptr, csr_src, csr_norm, AGG, n);
    mm22(AGG, W1T, b1, HA, 128, 64);
    // conv2: agg(HA)[.,128] -> @W2 relu -> HB[.,256]
    k_agg<128><<<aggB(4), tb, 0, stream>>>(HA, dinv, rowptr, csr_src, csr_norm, AGG, n);
    mm22(AGG, W2T, b2, HB, 256, 128);
    // conv3: agg(HB)[.,256] -> @W3 relu -> HA[.,512]
    k_agg<256><<<aggB(2), tb, 0, stream>>>(HB, dinv, rowptr, csr_src, csr_norm, AGG, n);
    mm22(AGG, W3T, b3, HA, 512, 256);
    // fc1: HA @ fW1 relu -> HB[.,512]
    mm22(HA, F1T, fb1, HB, 512, 512);
    // fc2: HB @ fW2 -> logits f32 [.,40]  (256x64 tiles: no dead columns)
    {
        int nwg = Mpad / 256;
        k_mm<4, 1, false, false><<<nwg, 256, 0, stream>>>(HB, F2T, fb2, nullptr, logits, n, 40, 512, 1, nwg);
    }
    // log_softmax
    k_lsm<<<waveB, tb, 0, stream>>>(logits, out, n);
}

// Round 8
// 205.957 us; speedup vs baseline: 3.4795x; 1.0651x over previous
//
#include <hip/hip_runtime.h>
#include <cstdint>
#include <cstddef>

// ---------------------------------------------------------------------------
// GCN 3-conv + MLP head. FP16 single-product MFMA GEMMs (f32 accumulate),
// f16 activations, aggregate-before-linear (A(xW) == (Ax)W, Fin<Fout).
// 256x256 8-wave GEMM (per-wave 128x64 -> MFMA-bound, not LDS-read-bound).
// fc2 GEMM fuses bias + log_softmax epilogue. Packed u64 degree atomic;
// CSR slots from atomic return -> atomic-free fill.
// ---------------------------------------------------------------------------

typedef _Float16 f16;
typedef _Float16 half8 __attribute__((ext_vector_type(8)));
typedef _Float16 half4 __attribute__((ext_vector_type(4)));
typedef float v4f __attribute__((ext_vector_type(4)));
typedef unsigned long long u64;

__device__ inline void gload_lds16(const void* g, void* l) {
    __builtin_amdgcn_global_load_lds(
        (const __attribute__((address_space(1))) unsigned int*)g,
        (__attribute__((address_space(3))) unsigned int*)l, 16, 0, 0);
}

// ------------------------------ graph prep --------------------------------

// one packed atomic per edge; old value -> CSR slot within dst bucket
__global__ __launch_bounds__(256) void k_edge1(const int* __restrict__ dst, const float* __restrict__ ew,
                                               u64* __restrict__ packed, int* __restrict__ eslot, int E) {
    int t = blockIdx.x * blockDim.x + threadIdx.x;
    int e0 = t * 4;
    if (e0 + 3 < E) {
        int4 d4 = *(const int4*)(dst + e0);
        float4 w4 = *(const float4*)(ew + e0);
        u64 a0 = ((u64)__float2uint_rn(w4.x * 1048576.f) << 24) | 1ULL;
        u64 a1 = ((u64)__float2uint_rn(w4.y * 1048576.f) << 24) | 1ULL;
        u64 a2 = ((u64)__float2uint_rn(w4.z * 1048576.f) << 24) | 1ULL;
        u64 a3 = ((u64)__float2uint_rn(w4.w * 1048576.f) << 24) | 1ULL;
        u64 o0 = atomicAdd(&packed[d4.x], a0);
        u64 o1 = atomicAdd(&packed[d4.y], a1);
        u64 o2 = atomicAdd(&packed[d4.z], a2);
        u64 o3 = atomicAdd(&packed[d4.w], a3);
        int4 s;
        s.x = (int)(o0 & 0xFFFFFF); s.y = (int)(o1 & 0xFFFFFF);
        s.z = (int)(o2 & 0xFFFFFF); s.w = (int)(o3 & 0xFFFFFF);
        *(int4*)(eslot + e0) = s;
    } else {
        for (int e = e0; e < E; ++e) {
            u64 a = ((u64)__float2uint_rn(ew[e] * 1048576.f) << 24) | 1ULL;
            u64 o = atomicAdd(&packed[dst[e]], a);
            eslot[e] = (int)(o & 0xFFFFFF);
        }
    }
}

// fused: dinv (Newton-refined rsqrt of unpacked degree) + per-block cnt sums
__global__ __launch_bounds__(256) void k_dinv_scan1(const u64* __restrict__ packed,
                                                    float* __restrict__ dinv, int* __restrict__ cnt,
                                                    int* __restrict__ bsum, int n) {
    int i = blockIdx.x * 256 + threadIdx.x;
    int c = 0;
    if (i < n) {
        u64 pk = packed[i];
        c = (int)(pk & 0xFFFFFF);
        float d = 1.0f + (float)(pk >> 24) * (1.0f / 1048576.f);  // self-loop + sum(ew)
        float r = rsqrtf(d);
        r = r * (1.5f - 0.5f * d * r * r);
        dinv[i] = r;
        cnt[i] = c;
    }
    int v = c;
#pragma unroll
    for (int o = 32; o; o >>= 1) v += __shfl_xor(v, o);
    __shared__ int s[4];
    if ((threadIdx.x & 63) == 0) s[threadIdx.x >> 6] = v;
    __syncthreads();
    if (threadIdx.x == 0) bsum[blockIdx.x] = s[0] + s[1] + s[2] + s[3];
}

// 256-thread inclusive block scan (shfl wave scan + LDS wave offsets).
__device__ inline int block_scan_incl(int v) {
    __shared__ int ws[4];
    int lane = threadIdx.x & 63, w = threadIdx.x >> 6;
#pragma unroll
    for (int off = 1; off < 64; off <<= 1) {
        int t = __shfl_up(v, off);
        if (lane >= off) v += t;
    }
    if (lane == 63) ws[w] = v;
    __syncthreads();
    int add = 0;
#pragma unroll
    for (int i = 0; i < 4; ++i) add += (i < w) ? ws[i] : 0;
    __syncthreads();
    return v + add;
}

// exclusive scan of block sums (single block)
__global__ __launch_bounds__(256) void k_scan2(const int* __restrict__ bsum, int* __restrict__ boff, int nb) {
    __shared__ int carry;
    if (threadIdx.x == 0) carry = 0;
    __syncthreads();
    for (int base = 0; base < nb; base += 256) {
        int i = base + threadIdx.x;
        int v = (i < nb) ? bsum[i] : 0;
        int incl = block_scan_incl(v);
        int c = carry;
        if (i < nb) boff[i] = c + incl - v;
        __syncthreads();
        if (threadIdx.x == 255) carry = c + incl;
        __syncthreads();
    }
}

// local exclusive scan + block offset -> rowptr[0..n)
__global__ __launch_bounds__(256) void k_scan3(const int* __restrict__ cnt, const int* __restrict__ boff,
                                               int* __restrict__ rowptr, int n) {
    int i = blockIdx.x * 256 + threadIdx.x;
    int v = (i < n) ? cnt[i] : 0;
    int incl = block_scan_incl(v);
    if (i < n) rowptr[i] = boff[blockIdx.x] + incl - v;
    if (i == n - 1) rowptr[n] = boff[blockIdx.x] + incl;  // total
}

// atomic-free CSR fill using precomputed slots
__global__ __launch_bounds__(256) void k_fill(const int* __restrict__ src, const int* __restrict__ dst,
                                              const float* __restrict__ ew, const int* __restrict__ eslot,
                                              const float* __restrict__ dinv, const int* __restrict__ rowptr,
                                              int* __restrict__ csr_src, float* __restrict__ csr_norm, int E) {
    int e = blockIdx.x * blockDim.x + threadIdx.x;
    if (e < E) {
        int d = dst[e], s = src[e];
        int idx = rowptr[d] + eslot[e];
        csr_src[idx] = s;
        csr_norm[idx] = dinv[s] * ew[e] * dinv[d];
    }
}

// fused: packed init + x f32->f16 cast + 5 weight transposes W[K,N]->WT[Np,K]
struct PrepArgs {
    u64* packed; int n;
    const float* x; f16* xh; int xt4;
    const float* W[5]; f16* WT[5];
    int lgK[5]; int N[5]; int off[6];
};
__global__ __launch_bounds__(256) void k_prep(PrepArgs a) {
    int i = blockIdx.x * 256 + threadIdx.x;
    if (i < a.n) { a.packed[i] = 0ULL; return; }
    int j = i - a.n;
    if (j < a.xt4) {
        float4 v = *(const float4*)(a.x + (size_t)j * 4);
        half4 h = {(f16)v.x, (f16)v.y, (f16)v.z, (f16)v.w};
        *(half4*)(a.xh + (size_t)j * 4) = h;
        return;
    }
    int w = j - a.xt4;
#pragma unroll
    for (int s = 0; s < 5; ++s) {
        if (w >= a.off[s] && w < a.off[s + 1]) {
            int li = w - a.off[s];
            int K = 1 << a.lgK[s];
            int nr = li >> a.lgK[s], k = li & (K - 1);
            float v = (nr < a.N[s]) ? a.W[s][(size_t)k * a.N[s] + nr] : 0.f;
            a.WT[s][li] = (f16)v;
        }
    }
}

// ------------------------------ aggregation -------------------------------
// out[i,:] = dinv[i]^2*h[i,:] + sum_j norm_j*h[src_j,:]; f16 in/out, f32 acc.
template <int F>
__global__ __launch_bounds__(256) void k_agg(const f16* __restrict__ h,
                                             const float* __restrict__ dinv, const int* __restrict__ rowptr,
                                             const int* __restrict__ csr_src, const float* __restrict__ csr_norm,
                                             f16* __restrict__ o, int n) {
    constexpr int LPN = F / 8;
    constexpr int NPW = 64 / LPN;
    int wave = (int)((blockIdx.x * (unsigned)blockDim.x + threadIdx.x) >> 6);
    int lane = threadIdx.x & 63;
    int grp = lane / LPN, lin = lane % LPN;
    int node = wave * NPW + grp;
    if (node >= n) return;
    float di = dinv[node], w0 = di * di;
    float acc[8];
#pragma unroll
    for (int i = 0; i < 8; ++i) acc[i] = 0.f;

    auto gat = [&](int s, float w) {
        half8 x = *(const half8*)(h + (size_t)s * F + lin * 8);
#pragma unroll
        for (int i = 0; i < 8; ++i) acc[i] += w * (float)x[i];
    };

    gat(node, w0);
    int beg = rowptr[node], end = rowptr[node + 1];
    int j = beg;
    for (; j + 3 < end; j += 4) {  // 4 independent gathers in flight
        int s0 = csr_src[j], s1 = csr_src[j + 1], s2 = csr_src[j + 2], s3 = csr_src[j + 3];
        float u0 = csr_norm[j], u1 = csr_norm[j + 1], u2 = csr_norm[j + 2], u3 = csr_norm[j + 3];
        gat(s0, u0); gat(s1, u1); gat(s2, u2); gat(s3, u3);
    }
    for (; j < end; ++j) gat(csr_src[j], csr_norm[j]);

    half8 v;
#pragma unroll
    for (int i = 0; i < 8; ++i) v[i] = (f16)acc[i];
    *(half8*)(o + (size_t)node * F + (size_t)lin * 8) = v;
}

// --------------------------- MFMA GEMM (small) ----------------------------
// 128x128 tile, 4 waves 2x2 (conv1 only). A,B via global_load_lds, dbuf.
template <bool RELU>
__global__ __launch_bounds__(256) void k_mm(const f16* __restrict__ A, const f16* __restrict__ BT,
                                            const float* __restrict__ bias, f16* __restrict__ Ch,
                                            int M, int N, int K, int nB, int nwg) {
    __shared__ f16 lsA[2][128 * 64];
    __shared__ f16 lsB[2][128 * 64];
    int wg = blockIdx.x;
    int q = nwg >> 3, r = nwg & 7;
    int xcd = wg & 7, lin = wg >> 3;
    int wgs = (xcd < r) ? (xcd * (q + 1) + lin) : (r * (q + 1) + (xcd - r) * q + lin);
    int bm = wgs / nB, bn = wgs % nB;

    int tid = threadIdx.x;
    int lane = tid & 63, wid = tid >> 6;
    int l16 = lane & 15, lhi = lane >> 4;
    int wm = (wid >> 1) * 64, wn = (wid & 1) * 64;
    int brow = bm * 128, bcol = bn * 128;

    v4f acc[4][4] = {};

    auto stageA = [&](int buf, int k0) {
#pragma unroll
        for (int it = 0; it < 4; ++it) {
            int b = it * 4096 + tid * 16;
            int row = b >> 7;
            int s = ((b >> 4) & 7) ^ (row & 7);
            gload_lds16(A + (size_t)(brow + row) * K + k0 + s * 8, ((char*)&lsA[buf][0]) + b);
        }
    };
    auto stageB = [&](int buf, int k0) {
#pragma unroll
        for (int it = 0; it < 4; ++it) {
            int b = it * 4096 + tid * 16;
            int row = b >> 7;
            int s = ((b >> 4) & 7) ^ (row & 7);
            gload_lds16(BT + (size_t)(bcol + row) * K + k0 + s * 8, ((char*)&lsB[buf][0]) + b);
        }
    };

    int nk = K >> 6;
    stageA(0, 0);
    stageB(0, 0);
    for (int kt = 0; kt < nk; ++kt) {
        int cur = kt & 1;
        __syncthreads();
        if (kt + 1 < nk) { stageA(cur ^ 1, (kt + 1) << 6); stageB(cur ^ 1, (kt + 1) << 6); }
#pragma unroll
        for (int ks = 0; ks < 2; ++ks) {
            half8 bf[4];
#pragma unroll
            for (int fn = 0; fn < 4; ++fn) {
                int row = wn + fn * 16 + l16;
                int sidx = (ks * 4 + lhi) ^ (row & 7);
                bf[fn] = *(const half8*)(&lsB[cur][0] + row * 64 + sidx * 8);
            }
#pragma unroll
            for (int fm = 0; fm < 4; ++fm) {
                int row = wm + fm * 16 + l16;
                int sidx = (ks * 4 + lhi) ^ (row & 7);
                half8 af = *(const half8*)(&lsA[cur][0] + row * 64 + sidx * 8);
#pragma unroll
                for (int fn = 0; fn < 4; ++fn)
                    acc[fm][fn] = __builtin_amdgcn_mfma_f32_16x16x32_f16(bf[fn], af, acc[fm][fn], 0, 0, 0);
            }
        }
    }
#pragma unroll
    for (int fm = 0; fm < 4; ++fm) {
        int m = brow + wm + fm * 16 + l16;
        if (m >= M) continue;
#pragma unroll
        for (int fn = 0; fn < 4; ++fn) {
            int nb = bcol + wn + fn * 16 + lhi * 4;
            v4f bv = *(const v4f*)(bias + nb);
            v4f v = acc[fm][fn] + bv;
            if (RELU) {
#pragma unroll
                for (int rr = 0; rr < 4; ++rr) v[rr] = fmaxf(v[rr], 0.f);
            }
            half4 hv = {(f16)v[0], (f16)v[1], (f16)v[2], (f16)v[3]};
            *(half4*)(Ch + (size_t)m * N + nb) = hv;
        }
    }
}

// --------------------------- MFMA GEMM (large) ----------------------------
// 256x256 tile, 8 waves (2Mx4N), per-wave 128x64 -> 24 ds_read vs 64 MFMA
// per k-step (MFMA-bound). LDS 128KB, 1 block/CU. BK=64, dbuf, one barrier.
template <bool RELU>
__global__ __launch_bounds__(512, 2) void k_mm8(const f16* __restrict__ A, const f16* __restrict__ BT,
                                                const float* __restrict__ bias, f16* __restrict__ Ch,
                                                int M, int N, int K, int nB, int nwg) {
    __shared__ f16 lsA[2][256 * 64];
    __shared__ f16 lsB[2][256 * 64];
    int wg = blockIdx.x;
    int q = nwg >> 3, r = nwg & 7;
    int xcd = wg & 7, lin = wg >> 3;
    int wgs = (xcd < r) ? (xcd * (q + 1) + lin) : (r * (q + 1) + (xcd - r) * q + lin);
    int bm = wgs / nB, bn = wgs % nB;

    int tid = threadIdx.x;
    int lane = tid & 63, wid = tid >> 6;
    int l16 = lane & 15, lhi = lane >> 4;
    int wm = (wid >> 2) * 128, wn = (wid & 3) * 64;
    int brow = bm * 256, bcol = bn * 256;

    v4f acc[8][4] = {};

    auto stageA = [&](int buf, int k0) {
#pragma unroll
        for (int it = 0; it < 4; ++it) {
            int b = it * 8192 + tid * 16;
            int row = b >> 7;
            int s = ((b >> 4) & 7) ^ (row & 7);
            gload_lds16(A + (size_t)(brow + row) * K + k0 + s * 8, ((char*)&lsA[buf][0]) + b);
        }
    };
    auto stageB = [&](int buf, int k0) {
#pragma unroll
        for (int it = 0; it < 4; ++it) {
            int b = it * 8192 + tid * 16;
            int row = b >> 7;
            int s = ((b >> 4) & 7) ^ (row & 7);
            gload_lds16(BT + (size_t)(bcol + row) * K + k0 + s * 8, ((char*)&lsB[buf][0]) + b);
        }
    };

    int nk = K >> 6;
    stageA(0, 0);
    stageB(0, 0);
    for (int kt = 0; kt < nk; ++kt) {
        int cur = kt & 1;
        __syncthreads();  // buf[cur] DMA drained; prior LDS reads done
        if (kt + 1 < nk) { stageA(cur ^ 1, (kt + 1) << 6); stageB(cur ^ 1, (kt + 1) << 6); }
#pragma unroll
        for (int ks = 0; ks < 2; ++ks) {
            half8 bf[4];
#pragma unroll
            for (int fn = 0; fn < 4; ++fn) {
                int row = wn + fn * 16 + l16;
                int sidx = (ks * 4 + lhi) ^ (row & 7);
                bf[fn] = *(const half8*)(&lsB[cur][0] + row * 64 + sidx * 8);
            }
#pragma unroll
            for (int fm = 0; fm < 8; ++fm) {
                int row = wm + fm * 16 + l16;
                int sidx = (ks * 4 + lhi) ^ (row & 7);
                half8 af = *(const half8*)(&lsA[cur][0] + row * 64 + sidx * 8);
#pragma unroll
                for (int fn = 0; fn < 4; ++fn)
                    acc[fm][fn] = __builtin_amdgcn_mfma_f32_16x16x32_f16(bf[fn], af, acc[fm][fn], 0, 0, 0);
            }
        }
    }
#pragma unroll
    for (int fm = 0; fm < 8; ++fm) {
        int m = brow + wm + fm * 16 + l16;
        if (m >= M) continue;
#pragma unroll
        for (int fn = 0; fn < 4; ++fn) {
            int nb = bcol + wn + fn * 16 + lhi * 4;
            v4f bv = *(const v4f*)(bias + nb);
            v4f v = acc[fm][fn] + bv;
            if (RELU) {
#pragma unroll
                for (int rr = 0; rr < 4; ++rr) v[rr] = fmaxf(v[rr], 0.f);
            }
            half4 hv = {(f16)v[0], (f16)v[1], (f16)v[2], (f16)v[3]};
            *(half4*)(Ch + (size_t)m * N + nb) = hv;
        }
    }
}

// ----------------------- fc2 GEMM + log_softmax ---------------------------
// 256x64 tile, 4 waves stacked in M; N=40 (BT padded to 64 rows). Epilogue
// computes log_softmax over the 40 classes in-register (each wave row's
// values live in 4 lanes x 16 regs; two shfl_xor reduces).
__global__ __launch_bounds__(256) void k_mmfc2(const f16* __restrict__ A, const f16* __restrict__ BT,
                                               const float* __restrict__ bias, float* __restrict__ out,
                                               int M, int K) {
    __shared__ f16 lsA[2][256 * 64];
    __shared__ f16 lsB[2][64 * 64];
    int bm = blockIdx.x;
    int tid = threadIdx.x;
    int lane = tid & 63, wid = tid >> 6;
    int l16 = lane & 15, lhi = lane >> 4;
    int wm = wid * 64;
    int brow = bm * 256;

    v4f acc[4][4] = {};

    auto stageA = [&](int buf, int k0) {
#pragma unroll
        for (int it = 0; it < 8; ++it) {
            int b = it * 4096 + tid * 16;
            int row = b >> 7;
            int s = ((b >> 4) & 7) ^ (row & 7);
            gload_lds16(A + (size_t)(brow + row) * K + k0 + s * 8, ((char*)&lsA[buf][0]) + b);
        }
    };
    auto stageB = [&](int buf, int k0) {
#pragma unroll
        for (int it = 0; it < 2; ++it) {
            int b = it * 4096 + tid * 16;
            int row = b >> 7;
            int s = ((b >> 4) & 7) ^ (row & 7);
            gload_lds16(BT + (size_t)row * K + k0 + s * 8, ((char*)&lsB[buf][0]) + b);
        }
    };

    int nk = K >> 6;
    stageA(0, 0);
    stageB(0, 0);
    for (int kt = 0; kt < nk; ++kt) {
        int cur = kt & 1;
        __syncthreads();
        if (kt + 1 < nk) { stageA(cur ^ 1, (kt + 1) << 6); stageB(cur ^ 1, (kt + 1) << 6); }
#pragma unroll
        for (int ks = 0; ks < 2; ++ks) {
            half8 bf[4];
#pragma unroll
            for (int fn = 0; fn < 4; ++fn) {
                int row = fn * 16 + l16;
                int sidx = (ks * 4 + lhi) ^ (row & 7);
                bf[fn] = *(const half8*)(&lsB[cur][0] + row * 64 + sidx * 8);
            }
#pragma unroll
            for (int fm = 0; fm < 4; ++fm) {
                int row = wm + fm * 16 + l16;
                int sidx = (ks * 4 + lhi) ^ (row & 7);
                half8 af = *(const half8*)(&lsA[cur][0] + row * 64 + sidx * 8);
#pragma unroll
                for (int fn = 0; fn < 4; ++fn)
                    acc[fm][fn] = __builtin_amdgcn_mfma_f32_16x16x32_f16(bf[fn], af, acc[fm][fn], 0, 0, 0);
            }
        }
    }

    // bias (same for all fm)
    float bv[4][4];
#pragma unroll
    for (int fn = 0; fn < 4; ++fn)
#pragma unroll
        for (int rr = 0; rr < 4; ++rr) {
            int nn = fn * 16 + lhi * 4 + rr;
            bv[fn][rr] = (nn < 40) ? bias[nn] : 0.f;
        }

#pragma unroll
    for (int fm = 0; fm < 4; ++fm) {
        int m = brow + wm + fm * 16 + l16;
        float v[4][4];
        float mx = -INFINITY;
#pragma unroll
        for (int fn = 0; fn < 4; ++fn)
#pragma unroll
            for (int rr = 0; rr < 4; ++rr) {
                int nn = fn * 16 + lhi * 4 + rr;
                v[fn][rr] = acc[fm][fn][rr] + bv[fn][rr];
                if (nn < 40) mx = fmaxf(mx, v[fn][rr]);
            }
        mx = fmaxf(mx, __shfl_xor(mx, 16));
        mx = fmaxf(mx, __shfl_xor(mx, 32));
        float s = 0.f;
#pragma unroll
        for (int fn = 0; fn < 3; ++fn)
#pragma unroll
            for (int rr = 0; rr < 4; ++rr) {
                int nn = fn * 16 + lhi * 4 + rr;
                if (nn < 40) s += __expf(v[fn][rr] - mx);
            }
        s += __shfl_xor(s, 16);
        s += __shfl_xor(s, 32);
        float ls = __logf(s);
        if (m < M) {
#pragma unroll
            for (int fn = 0; fn < 3; ++fn)
#pragma unroll
                for (int rr = 0; rr < 4; ++rr) {
                    int nn = fn * 16 + lhi * 4 + rr;
                    if (nn < 40) out[(size_t)m * 40 + nn] = v[fn][rr] - mx - ls;
                }
        }
    }
}

// ------------------------------ host --------------------------------------

extern "C" void kernel_launch(void* const* d_in, const int* in_sizes, int n_in,
                              void* d_out, int out_size, void* d_ws, size_t ws_size,
                              hipStream_t stream) {
    const float* x   = (const float*)d_in[0];
    const int*   ei  = (const int*)d_in[1];
    const float* ea  = (const float*)d_in[2];
    const float* W1  = (const float*)d_in[3];  const float* b1  = (const float*)d_in[4];
    const float* W2  = (const float*)d_in[5];  const float* b2  = (const float*)d_in[6];
    const float* W3  = (const float*)d_in[7];  const float* b3  = (const float*)d_in[8];
    const float* fW1 = (const float*)d_in[9];  const float* fb1 = (const float*)d_in[10];
    const float* fW2 = (const float*)d_in[11]; const float* fb2 = (const float*)d_in[12];

    int n = in_sizes[0] / 64;
    int E = in_sizes[1] / 2;
    int Mpad = ((n + 255) / 256) * 256;
    const int* src = ei;
    const int* dst = ei + E;
    float* out = (float*)d_out;

    char* p = (char*)d_ws;
    auto alloc = [&](size_t bytes) -> char* {
        char* r = p;
        p += (bytes + 255) & ~(size_t)255;
        return r;
    };
    int nb256 = (n + 255) / 256;
    u64*   packed   = (u64*)alloc((size_t)n * 8);
    float* dinv     = (float*)alloc((size_t)n * 4);
    int*   cnt      = (int*)alloc((size_t)n * 4);
    int*   rowptr   = (int*)alloc((size_t)(n + 1) * 4);
    int*   bsum     = (int*)alloc((size_t)nb256 * 4);
    int*   boff     = (int*)alloc((size_t)nb256 * 4);
    int*   eslot    = (int*)alloc((size_t)E * 4);
    int*   csr_src  = (int*)alloc((size_t)E * 4);
    float* csr_norm = (float*)alloc((size_t)E * 4);
    f16* XH  = (f16*)alloc((size_t)Mpad * 64 * 2);
    f16* W1T = (f16*)alloc((size_t)128 * 64 * 2);
    f16* W2T = (f16*)alloc((size_t)256 * 128 * 2);
    f16* W3T = (f16*)alloc((size_t)512 * 256 * 2);
    f16* F1T = (f16*)alloc((size_t)512 * 512 * 2);
    f16* F2T = (f16*)alloc((size_t)64 * 512 * 2);
    f16* AGG = (f16*)alloc((size_t)Mpad * 256 * 2);
    f16* HA  = (f16*)alloc((size_t)Mpad * 512 * 2);
    f16* HB  = (f16*)alloc((size_t)Mpad * 512 * 2);

    const int tb = 256;
    int eB = (E + tb - 1) / tb;
    int e4B = (E / 4 + tb - 1) / tb + 1;
    auto aggB = [&](int npw) {
        long waves = (n + npw - 1) / npw;
        return (int)((waves * 64 + tb - 1) / tb);
    };

    // fused prep: packed init + x-cast + weight transposes (must precede edge1)
    {
        PrepArgs a;
        a.packed = packed; a.n = n;
        a.x = x; a.xh = XH; a.xt4 = n * 16;
        a.W[0] = W1;  a.WT[0] = W1T; a.lgK[0] = 6; a.N[0] = 128;
        a.W[1] = W2;  a.WT[1] = W2T; a.lgK[1] = 7; a.N[1] = 256;
        a.W[2] = W3;  a.WT[2] = W3T; a.lgK[2] = 8; a.N[2] = 512;
        a.W[3] = fW1; a.WT[3] = F1T; a.lgK[3] = 9; a.N[3] = 512;
        a.W[4] = fW2; a.WT[4] = F2T; a.lgK[4] = 9; a.N[4] = 40;
        a.off[0] = 0;
        a.off[1] = a.off[0] + 128 * 64;
        a.off[2] = a.off[1] + 256 * 128;
        a.off[3] = a.off[2] + 512 * 256;
        a.off[4] = a.off[3] + 512 * 512;
        a.off[5] = a.off[4] + 64 * 512;
        int tot = a.n + a.xt4 + a.off[5];
        k_prep<<<(tot + tb - 1) / tb, tb, 0, stream>>>(a);
    }

    // graph prep
    k_edge1<<<e4B, tb, 0, stream>>>(dst, ea, packed, eslot, E);
    k_dinv_scan1<<<nb256, tb, 0, stream>>>(packed, dinv, cnt, bsum, n);
    k_scan2<<<1, tb, 0, stream>>>(bsum, boff, nb256);
    k_scan3<<<nb256, tb, 0, stream>>>(cnt, boff, rowptr, n);
    k_fill<<<eB, tb, 0, stream>>>(src, dst, ea, eslot, dinv, rowptr, csr_src, csr_norm, E);

    auto mm8 = [&](const f16* a, const f16* bt, const float* bias, f16* ch, int N, int K) {
        int nB2 = N / 256;
        int nwg = (Mpad / 256) * nB2;
        k_mm8<true><<<nwg, 512, 0, stream>>>(a, bt, bias, ch, n, N, K, nB2, nwg);
    };

    // conv1: agg(xh)[.,64] -> @W1 relu -> HA[.,128]   (128x128 tile kernel)
    k_agg<64><<<aggB(8), tb, 0, stream>>>(XH, dinv, rowptr, csr_src, csr_norm, AGG, n);
    {
        int nwg = Mpad / 128;
        k_mm<true><<<nwg, 256, 0, stream>>>(AGG, W1T, b1, HA, n, 128, 64, 1, nwg);
    }
    // conv2: agg(HA)[.,128] -> @W2 relu -> HB[.,256]
    k_agg<128><<<aggB(4), tb, 0, stream>>>(HA, dinv, rowptr, csr_src, csr_norm, AGG, n);
    mm8(AGG, W2T, b2, HB, 256, 128);
    // conv3: agg(HB)[.,256] -> @W3 relu -> HA[.,512]
    k_agg<256><<<aggB(2), tb, 0, stream>>>(HB, dinv, rowptr, csr_src, csr_norm, AGG, n);
    mm8(AGG, W3T, b3, HA, 512, 256);
    // fc1: HA @ fW1 relu -> HB[.,512]
    mm8(HA, F1T, fb1, HB, 512, 512);
    // fc2 + log_softmax fused -> out
    k_mmfc2<<<Mpad / 256, 256, 0, stream>>>(HB, F2T, fb2, out, n, 512);
}